// Round 1
// baseline (1633.657 us; speedup 1.0000x reference)
//
#include <hip/hip_runtime.h>

typedef unsigned short u16;
typedef short s16x8 __attribute__((ext_vector_type(8)));
typedef float f32x4 __attribute__((ext_vector_type(4)));

__device__ __forceinline__ u16 f2bf(float f) {
    unsigned int u = __float_as_uint(f);
    u = (u + 0x7fffu + ((u >> 16) & 1u)) >> 16;
    return (u16)u;
}

__device__ __forceinline__ float wave_sum64(float v) {
#pragma unroll
    for (int off = 32; off; off >>= 1) v += __shfl_xor(v, off, 64);
    return v;
}

// ---------------- misc ----------------
__global__ void k_zero(float* p, int n) {
    int i = blockIdx.x * blockDim.x + threadIdx.x;
    if (i < n) p[i] = 0.f;
}

// conv1 weight transpose: (co,ci,ky,kx) -> [k=(ci*81+ky*9+kx)][co], fp32
__global__ void k_w1t(const float* __restrict__ w, float* __restrict__ wt) {
    int i = blockIdx.x * 256 + threadIdx.x;
    if (i >= 243 * 256) return;
    int k = i >> 8, co = i & 255;
    wt[i] = w[co * 243 + k];
}

// prim weight transpose: (co,ci,ky,kx) -> bf16 [co][(ky*9+kx)*256 + ci]
__global__ void k_w2t(const float* __restrict__ w, u16* __restrict__ wt) {
    int co = blockIdx.x;   // 256
    int ci = threadIdx.x;  // 256
    const float* src = w + (co * 256 + ci) * 81;
    u16* dst = wt + co * 20736 + ci;
#pragma unroll 1
    for (int kk = 0; kk < 81; ++kk)
        dst[kk * 256] = f2bf(src[kk]);
}

// ---------------- conv1 + relu -> h bf16 NHWC [8][88][88][256] ----------------
__global__ __launch_bounds__(256) void k_conv1(
    const float* __restrict__ x, const float* __restrict__ w1t,
    const float* __restrict__ b1, u16* __restrict__ h)
{
    __shared__ float xs[3 * 9 * 96];
    int nb = blockIdx.x;          // 0..703
    int n = nb / 88, y = nb % 88;
    int co = threadIdx.x;
    for (int i = threadIdx.x; i < 3 * 9 * 96; i += 256) {
        int ci = i / 864;
        int rem = i - ci * 864;
        int yy = rem / 96, xx = rem - yy * 96;
        xs[i] = x[((n * 3 + ci) * 96 + (y + yy)) * 96 + xx];
    }
    __syncthreads();
    float bias = b1[co];
#pragma unroll 1
    for (int xo = 0; xo < 8; ++xo) {
        float acc[11];
#pragma unroll
        for (int j = 0; j < 11; ++j) acc[j] = bias;
        const int xb = xo * 11;
#pragma unroll 1
        for (int cik = 0; cik < 27; ++cik) {   // ci*9+ky
            float win[19];
            const float* row = &xs[cik * 96 + xb];
#pragma unroll
            for (int t = 0; t < 19; ++t) win[t] = row[t];
            const float* wrow = w1t + cik * 9 * 256 + co;
#pragma unroll
            for (int kx = 0; kx < 9; ++kx) {
                float wv = wrow[kx * 256];
#pragma unroll
                for (int j = 0; j < 11; ++j)
                    acc[j] = fmaf(win[kx + j], wv, acc[j]);
            }
        }
        u16* hp = h + ((n * 88 + y) * 88 + xb) * 256 + co;
#pragma unroll
        for (int j = 0; j < 11; ++j) {
            float v = acc[j] > 0.f ? acc[j] : 0.f;
            hp[j * 256] = f2bf(v);
        }
    }
}

// ---------------- prim conv as implicit GEMM, bf16 MFMA ----------------
// uT[co][p] = sum_k Wt[co][k] * A[p][k] + prim_b[co]
// A[p][(ky*9+kx)*256+ci] = h[n][2y+ky][2x+kx][ci],  p = n*1600 + y*40 + x
__global__ __launch_bounds__(256) void k_gemm2(
    const u16* __restrict__ hA, const u16* __restrict__ Wt,
    const float* __restrict__ pb, float* __restrict__ uT)
{
    __shared__ __align__(16) u16 As[2][128 * 64];
    __shared__ __align__(16) u16 Bs[2][128 * 64];

    int blk = blockIdx.x;           // 0..199
    int xcd = blk & 7;
    int half = xcd >> 2;            // channel half: XCDs 0-3 -> 0, 4-7 -> 1 (L2 locality)
    int mt = (blk >> 3) * 4 + (xcd & 3);  // 0..99
    int m0 = mt * 128;
    int n0 = half * 128;

    int tid = threadIdx.x;
    int wave = tid >> 6;
    int lane = tid & 63;
    int lr = lane >> 3;   // row within 8
    int lc = lane & 7;    // 16B column group

    int pbase[4], brow[4];
#pragma unroll
    for (int ii = 0; ii < 4; ++ii) {
        int row = wave * 32 + ii * 8 + lr;
        int p = m0 + row;
        int n = p / 1600;
        int rem = p - n * 1600;
        int yy = rem / 40;
        int xx = rem - yy * 40;
        pbase[ii] = ((n * 88 + 2 * yy) * 88 + 2 * xx) * 256;
        brow[ii] = (n0 + row) * 20736;
    }

    f32x4 acc[4][4];
#pragma unroll
    for (int i = 0; i < 4; ++i)
#pragma unroll
        for (int j = 0; j < 4; ++j) acc[i][j] = (f32x4){0.f, 0.f, 0.f, 0.f};

    int wm = wave & 1;   // channel 64-half within tile
    int wn = wave >> 1;  // pixel 64-half

    const int NS = 324;  // 81 * (256/64)

    // prologue: stage step 0 into buffer 0 (koff = 0)
#pragma unroll
    for (int ii = 0; ii < 4; ++ii) {
        const u16* ga = hA + pbase[ii] + lc * 8;
        u16* la = &As[0][(wave * 32 + ii * 8) * 64];
        __builtin_amdgcn_global_load_lds((const __attribute__((address_space(1))) void*)ga,
                                         (__attribute__((address_space(3))) void*)la, 16, 0, 0);
        const u16* gb = Wt + brow[ii] + lc * 8;
        u16* lb = &Bs[0][(wave * 32 + ii * 8) * 64];
        __builtin_amdgcn_global_load_lds((const __attribute__((address_space(1))) void*)gb,
                                         (__attribute__((address_space(3))) void*)lb, 16, 0, 0);
    }
    __syncthreads();

#pragma unroll 2
    for (int ks = 0; ks < NS; ++ks) {
        int cur = ks & 1;
        if (ks + 1 < NS) {           // prefetch next tile into other buffer
            int kn = ks + 1;
            int kykx = kn >> 2;
            int ci0 = (kn & 3) << 6;
            int ky = kykx / 9, kx = kykx - ky * 9;
            int koff = (ky * 88 + kx) * 256 + ci0;
            int kb = kn * 64;
#pragma unroll
            for (int ii = 0; ii < 4; ++ii) {
                const u16* ga = hA + pbase[ii] + koff + lc * 8;
                u16* la = &As[cur ^ 1][(wave * 32 + ii * 8) * 64];
                __builtin_amdgcn_global_load_lds((const __attribute__((address_space(1))) void*)ga,
                                                 (__attribute__((address_space(3))) void*)la, 16, 0, 0);
                const u16* gb = Wt + brow[ii] + kb + lc * 8;
                u16* lb = &Bs[cur ^ 1][(wave * 32 + ii * 8) * 64];
                __builtin_amdgcn_global_load_lds((const __attribute__((address_space(1))) void*)gb,
                                                 (__attribute__((address_space(3))) void*)lb, 16, 0, 0);
            }
        }
#pragma unroll
        for (int kk = 0; kk < 2; ++kk) {
            s16x8 af[4], bfr[4];
            int kcol = kk * 32 + (lane >> 4) * 8;
#pragma unroll
            for (int mi = 0; mi < 4; ++mi) {
                int rowc = wm * 64 + mi * 16 + (lane & 15);
                af[mi] = *(const s16x8*)&Bs[cur][rowc * 64 + kcol];
            }
#pragma unroll
            for (int ni = 0; ni < 4; ++ni) {
                int rowp = wn * 64 + ni * 16 + (lane & 15);
                bfr[ni] = *(const s16x8*)&As[cur][rowp * 64 + kcol];
            }
#pragma unroll
            for (int mi = 0; mi < 4; ++mi)
#pragma unroll
                for (int ni = 0; ni < 4; ++ni)
                    acc[mi][ni] = __builtin_amdgcn_mfma_f32_16x16x32_bf16(
                        af[mi], bfr[ni], acc[mi][ni], 0, 0, 0);
        }
        __syncthreads();   // drains prefetch (vmcnt) + guards LDS reuse
    }

    // epilogue: D[m=channel][n=pixel]; lane: n = lane&15, m = (lane>>4)*4 + reg
#pragma unroll
    for (int mi = 0; mi < 4; ++mi) {
        int co = n0 + wm * 64 + mi * 16 + (lane >> 4) * 4;
#pragma unroll
        for (int ni = 0; ni < 4; ++ni) {
            int p = m0 + wn * 64 + ni * 16 + (lane & 15);
#pragma unroll
            for (int r = 0; r < 4; ++r)
                uT[(co + r) * 12800 + p] = acc[mi][ni][r] + pb[co + r];
        }
    }
}

// ---------------- squash + u_hat ----------------
// capsule (b, r): c=r/50, s=r%50; elems = uT[c*12800 + b*1600 + s*32 + t]
// uh layout: [c][b][r]
__global__ __launch_bounds__(256) void k_squash_uhat(
    const float* __restrict__ uT, const float* __restrict__ dW, float* __restrict__ uh)
{
    int t = threadIdx.x & 31;
    int g = threadIdx.x >> 5;
    int cap = blockIdx.x * 8 + g;      // b*12800 + r
    int b = cap / 12800;
    int r = cap - b * 12800;
    int c = r / 50;
    int s = r - c * 50;
    float u = uT[c * 12800 + b * 1600 + s * 32 + t];
    float sn = u * u;
#pragma unroll
    for (int off = 16; off; off >>= 1) sn += __shfl_xor(sn, off, 32);
    float scale = sqrtf(sn) / (1.0f + sn);
    float us = u * scale;
    const float* wp = dW + r * 320 + t;
#pragma unroll 1
    for (int cc = 0; cc < 10; ++cc) {
        float p = wp[cc * 32] * us;
#pragma unroll
        for (int off = 16; off; off >>= 1) p += __shfl_xor(p, off, 32);
        if (t == 0) uh[(cc * 8 + b) * 12800 + r] = p;
    }
}

// ---------------- routing ----------------
// accum layout: [10 Z][80 S(c*8+b)]
__global__ __launch_bounds__(256) void k_route1(
    const float* __restrict__ uh, const float* __restrict__ bcr,
    float* __restrict__ accum, int first)
{
    int r = blockIdx.x * 256 + threadIdx.x;   // 12800 exact
    int lane0 = ((threadIdx.x & 63) == 0);
#pragma unroll 1
    for (int c = 0; c < 10; ++c) {
        float e = first ? 1.0f : expf(bcr[c * 12800 + r]);
        float se = wave_sum64(e);
        if (lane0) atomicAdd(&accum[c], se);
#pragma unroll 1
        for (int b = 0; b < 8; ++b) {
            float p = e * uh[(c * 8 + b) * 12800 + r];
            float sp = wave_sum64(p);
            if (lane0) atomicAdd(&accum[10 + c * 8 + b], sp);
        }
    }
}

__global__ void k_route2(const float* __restrict__ accum, float* __restrict__ vbuf,
                         float* __restrict__ out, int first, int writeOut)
{
    int i = threadIdx.x;
    if (i >= 80) return;
    int b = i / 10, c = i - b * 10;
    float Z = first ? 12800.0f : accum[c];
    float S = accum[10 + c * 8 + b];
    float s = S / Z;
    float v = s * fabsf(s) / (1.0f + s * s);
    vbuf[i] = v;                 // [b*10+c]
    if (writeOut) out[i] = v;    // v output (8,10,1)
}

__global__ __launch_bounds__(256) void k_route3(
    const float* __restrict__ uh, const float* __restrict__ vbuf,
    float* __restrict__ bcr, int first)
{
    int r = blockIdx.x * 256 + threadIdx.x;
#pragma unroll 1
    for (int c = 0; c < 10; ++c) {
        float a = 0.f;
#pragma unroll
        for (int b = 0; b < 8; ++b)
            a += uh[(c * 8 + b) * 12800 + r] * vbuf[b * 10 + c];
        bcr[c * 12800 + r] = first ? a : (bcr[c * 12800 + r] + a);
    }
}

// ---------------- decoder ----------------
__global__ void k_dec1(const float* __restrict__ vbuf, const float* __restrict__ w1,
                       const float* __restrict__ b1, float* __restrict__ r1)
{
    __shared__ float ts[80];
    int j = threadIdx.x;  // 512
    if (j < 80) ts[j] = vbuf[j];
    __syncthreads();
    float acc[8];
    float bb = b1[j];
#pragma unroll
    for (int b = 0; b < 8; ++b) acc[b] = bb;
#pragma unroll 1
    for (int k = 0; k < 10; ++k) {
        float wv = w1[k * 512 + j];
#pragma unroll
        for (int b = 0; b < 8; ++b) acc[b] = fmaf(ts[b * 10 + k], wv, acc[b]);
    }
#pragma unroll
    for (int b = 0; b < 8; ++b) r1[b * 512 + j] = fmaxf(acc[b], 0.f);
}

__global__ __launch_bounds__(256) void k_dec2(
    const float* __restrict__ r1, const float* __restrict__ w2,
    const float* __restrict__ b2, float* __restrict__ r2)
{
    __shared__ float s1[8 * 512];
    int tid = threadIdx.x;
    for (int i = tid; i < 4096; i += 256) s1[i] = r1[i];
    __syncthreads();
    int j = blockIdx.x * 256 + tid;  // 1024
    float acc[8];
    float bb = b2[j];
#pragma unroll
    for (int b = 0; b < 8; ++b) acc[b] = bb;
#pragma unroll 2
    for (int k = 0; k < 512; ++k) {
        float wv = w2[k * 1024 + j];
#pragma unroll
        for (int b = 0; b < 8; ++b) acc[b] = fmaf(s1[b * 512 + k], wv, acc[b]);
    }
#pragma unroll
    for (int b = 0; b < 8; ++b) r2[b * 1024 + j] = fmaxf(acc[b], 0.f);
}

__global__ __launch_bounds__(128) void k_dec3(
    const float* __restrict__ r2, const float* __restrict__ w3,
    const float* __restrict__ b3, float* __restrict__ out)
{
    __shared__ float s2[8 * 1024];
    int tid = threadIdx.x;
    for (int i = tid; i < 8192; i += 128) s2[i] = r2[i];
    __syncthreads();
    int j = blockIdx.x * 128 + tid;  // 27648
    float acc[8];
    float bb = b3[j];
#pragma unroll
    for (int b = 0; b < 8; ++b) acc[b] = bb;
#pragma unroll 2
    for (int k = 0; k < 1024; ++k) {
        float wv = w3[k * 27648 + j];
#pragma unroll
        for (int b = 0; b < 8; ++b) acc[b] = fmaf(s2[b * 1024 + k], wv, acc[b]);
    }
#pragma unroll
    for (int b = 0; b < 8; ++b)
        out[80 + b * 27648 + j] = 1.0f / (1.0f + expf(-acc[b]));
}

// ---------------- launch ----------------
extern "C" void kernel_launch(void* const* d_in, const int* in_sizes, int n_in,
                              void* d_out, int out_size, void* d_ws, size_t ws_size,
                              hipStream_t stream)
{
    const float* x     = (const float*)d_in[0];
    const float* c1w   = (const float*)d_in[1];
    const float* c1b   = (const float*)d_in[2];
    const float* pw    = (const float*)d_in[3];
    const float* pbias = (const float*)d_in[4];
    const float* dW    = (const float*)d_in[5];
    const float* dw1   = (const float*)d_in[6];
    const float* db1   = (const float*)d_in[7];
    const float* dw2   = (const float*)d_in[8];
    const float* db2   = (const float*)d_in[9];
    const float* dw3   = (const float*)d_in[10];
    const float* db3   = (const float*)d_in[11];
    float* out = (float*)d_out;

    char* ws = (char*)d_ws;
    u16*   h     = (u16*)(ws);                    // 31,719,424 B
    u16*   wt2   = (u16*)(ws + 31719424);         // 10,616,832 B
    float* w1t   = (float*)(ws + 42336256);       //    248,832 B
    float* uT    = (float*)(ws + 42585088);       // 13,107,200 B
    float* uh    = (float*)(ws + 55692288);       //  4,096,000 B
    float* bcr   = (float*)(ws + 59788288);       //    512,000 B
    float* accum = (float*)(ws + 60300288);       //      1,152 B (3 x 96)
    float* vbuf  = (float*)(ws + 60301440);       //        320 B
    float* r1    = (float*)(ws + 60301760);       //     16,384 B
    float* r2    = (float*)(ws + 60318144);       //     32,768 B  -> total ~60.4 MB

    k_zero<<<2, 256, 0, stream>>>(accum, 368);            // accum(288) + vbuf(80)
    k_w1t<<<243, 256, 0, stream>>>(c1w, w1t);
    k_w2t<<<256, 256, 0, stream>>>(pw, wt2);
    k_conv1<<<704, 256, 0, stream>>>(x, w1t, c1b, h);
    k_gemm2<<<200, 256, 0, stream>>>(h, wt2, pbias, uT);
    k_squash_uhat<<<12800, 256, 0, stream>>>(uT, dW, uh);

    // routing iter 0 (b_ij = 0 -> uniform softmax; never reads poisoned bcr)
    k_route1<<<50, 256, 0, stream>>>(uh, bcr, accum, 1);
    k_route2<<<1, 128, 0, stream>>>(accum, vbuf, out, 1, 0);
    k_route3<<<50, 256, 0, stream>>>(uh, vbuf, bcr, 1);
    // iter 1
    k_route1<<<50, 256, 0, stream>>>(uh, bcr, accum + 96, 0);
    k_route2<<<1, 128, 0, stream>>>(accum + 96, vbuf, out, 0, 0);
    k_route3<<<50, 256, 0, stream>>>(uh, vbuf, bcr, 0);
    // iter 2 (final: writes v to out[0:80))
    k_route1<<<50, 256, 0, stream>>>(uh, bcr, accum + 192, 0);
    k_route2<<<1, 128, 0, stream>>>(accum + 192, vbuf, out, 0, 1);

    k_dec1<<<1, 512, 0, stream>>>(vbuf, dw1, db1, r1);
    k_dec2<<<4, 256, 0, stream>>>(r1, dw2, db2, r2);
    k_dec3<<<216, 128, 0, stream>>>(r2, dw3, db3, out);
}

// Round 2
// 673.191 us; speedup vs baseline: 2.4267x; 2.4267x over previous
//
#include <hip/hip_runtime.h>

typedef unsigned short u16;
typedef short s16x8 __attribute__((ext_vector_type(8)));
typedef float f32x4 __attribute__((ext_vector_type(4)));

__device__ __forceinline__ u16 f2bf(float f) {
    unsigned int u = __float_as_uint(f);
    u = (u + 0x7fffu + ((u >> 16) & 1u)) >> 16;
    return (u16)u;
}

__device__ __forceinline__ float wave_sum64(float v) {
#pragma unroll
    for (int off = 32; off; off >>= 1) v += __shfl_xor(v, off, 64);
    return v;
}

// ---------------- misc ----------------
__global__ void k_zero(float* __restrict__ p, int n) {
    int i = blockIdx.x * blockDim.x + threadIdx.x;
    if (i < n) p[i] = 0.f;
}

// conv1 weight transpose: (co,ci,ky,kx) -> [k=(ci*81+ky*9+kx)][co], fp32
__global__ void k_w1t(const float* __restrict__ w, float* __restrict__ wt) {
    int i = blockIdx.x * 256 + threadIdx.x;
    if (i >= 243 * 256) return;
    int k = i >> 8, co = i & 255;
    wt[i] = w[co * 243 + k];
}

// prim weight transpose via LDS: (co,ci,ky,kx) -> bf16 [co][(ky*9+kx)*256 + ci]
// block = (co, ci-half): reads and writes both coalesced.
__global__ __launch_bounds__(256) void k_w2t(const float* __restrict__ w, u16* __restrict__ wt) {
    __shared__ float ls[10368];
    int co = blockIdx.x >> 1;
    int half = blockIdx.x & 1;
    const float* src = w + (co * 256 + half * 128) * 81;
    for (int i = threadIdx.x; i < 10368; i += 256) ls[i] = src[i];
    __syncthreads();
    int ci = threadIdx.x & 127;
    int k2 = threadIdx.x >> 7;
    u16* dst = wt + co * 20736 + half * 128 + ci;
#pragma unroll 1
    for (int kk = k2; kk < 81; kk += 2)
        dst[kk * 256] = f2bf(ls[ci * 81 + kk]);
}

// ---------------- conv1 + relu -> h bf16 NHWC [8][88][88][256] ----------------
__global__ __launch_bounds__(256) void k_conv1(
    const float* __restrict__ x, const float* __restrict__ w1t,
    const float* __restrict__ b1, u16* __restrict__ h)
{
    __shared__ __align__(16) float xs[3 * 9 * 96 + 8];
    int nb = blockIdx.x;          // 0..703
    int n = nb / 88, y = nb % 88;
    int co = threadIdx.x;
    for (int i = threadIdx.x; i < 3 * 9 * 96; i += 256) {
        int ci = i / 864;
        int rem = i - ci * 864;
        int yy = rem / 96, xx = rem - yy * 96;
        xs[i] = x[((n * 3 + ci) * 96 + (y + yy)) * 96 + xx];
    }
    __syncthreads();
    float bias = b1[co];
#pragma unroll 1
    for (int xo = 0; xo < 6; ++xo) {   // 16B-aligned window tiles of 16 (last: 8 valid)
        const int xb = xo * 16;
        float acc[16];
#pragma unroll
        for (int j = 0; j < 16; ++j) acc[j] = bias;
#pragma unroll 1
        for (int cik = 0; cik < 27; ++cik) {   // ci*9+ky
            float win[24];
            const float4* row4 = (const float4*)&xs[cik * 96 + xb];
#pragma unroll
            for (int t = 0; t < 6; ++t) ((float4*)win)[t] = row4[t];
            const float* wrow = w1t + cik * 9 * 256 + co;
#pragma unroll
            for (int kx = 0; kx < 9; ++kx) {
                float wv = wrow[kx * 256];
#pragma unroll
                for (int j = 0; j < 16; ++j)
                    acc[j] = fmaf(win[kx + j], wv, acc[j]);
            }
        }
        int wlim = 88 - xb; if (wlim > 16) wlim = 16;
        u16* hp = h + ((n * 88 + y) * 88 + xb) * 256 + co;
#pragma unroll
        for (int j = 0; j < 16; ++j) {
            if (j < wlim) {
                float v = acc[j] > 0.f ? acc[j] : 0.f;
                hp[j * 256] = f2bf(v);
            }
        }
    }
}

// ---------------- prim conv as implicit GEMM, bf16 MFMA, K-split ----------------
// uTp[kq][co][p] = sum_{k in slice kq} Wt[co][k] * A[p][k]
// A[p][(ky*9+kx)*256+ci] = h[n][2y+ky][2x+kx][ci],  p = n*1600 + y*40 + x
// LDS columns XOR-swizzled: LDS(row, cg) holds global (row, cg ^ (row&7)).
__global__ __launch_bounds__(256) void k_gemm2(
    const u16* __restrict__ hA, const u16* __restrict__ Wt,
    float* __restrict__ uTp, int nkq_sh)
{
    __shared__ __align__(16) u16 As[128 * 64];
    __shared__ __align__(16) u16 Bs[128 * 64];

    int blk = blockIdx.x;
    int kq = blk & ((1 << nkq_sh) - 1);
    int rest = blk >> nkq_sh;        // 0..199
    int xcd = rest & 7;
    int halfn = xcd >> 2;            // channel half (L2 locality)
    int mt = (rest >> 3) * 4 + (xcd & 3);
    int m0 = mt * 128;
    int n0 = halfn * 128;
    const int NS = 324 >> nkq_sh;
    const int G0 = kq * NS;

    int tid = threadIdx.x;
    int wave = tid >> 6;
    int lane = tid & 63;
    int lr = lane >> 3;
    int lc = lane & 7;
    int swz = (lc ^ lr) << 3;        // swizzled element offset within 64-chunk

    int pbase[4], brow[4];
#pragma unroll
    for (int ii = 0; ii < 4; ++ii) {
        int row = wave * 32 + ii * 8 + lr;
        int p = m0 + row;
        int n = p / 1600;
        int rem = p - n * 1600;
        int yy = rem / 40;
        int xx = rem - yy * 40;
        pbase[ii] = ((n * 88 + 2 * yy) * 88 + 2 * xx) * 256 + swz;
        brow[ii] = (n0 + row) * 20736 + swz;
    }

    f32x4 acc[4][4];
#pragma unroll
    for (int i = 0; i < 4; ++i)
#pragma unroll
        for (int j = 0; j < 4; ++j) acc[i][j] = (f32x4){0.f, 0.f, 0.f, 0.f};

    int wm = wave & 1;
    int wn = wave >> 1;
    int l15 = lane & 15;
    int q = lane >> 4;
    int l7 = lane & 7;

#pragma unroll 1
    for (int ks = 0; ks < NS; ++ks) {
        int G = G0 + ks;
        int kykx = G >> 2;
        int ci0 = (G & 3) << 6;
        int ky = kykx / 9;
        int kx = kykx - ky * 9;
        int koff = (ky * 88 + kx) * 256 + ci0;
        int kb = G << 6;
#pragma unroll
        for (int ii = 0; ii < 4; ++ii) {
            const u16* ga = hA + pbase[ii] + koff;
            u16* la = &As[(wave * 32 + ii * 8) * 64];
            __builtin_amdgcn_global_load_lds((const __attribute__((address_space(1))) void*)ga,
                                             (__attribute__((address_space(3))) void*)la, 16, 0, 0);
            const u16* gb = Wt + brow[ii] + kb;
            u16* lb = &Bs[(wave * 32 + ii * 8) * 64];
            __builtin_amdgcn_global_load_lds((const __attribute__((address_space(1))) void*)gb,
                                             (__attribute__((address_space(3))) void*)lb, 16, 0, 0);
        }
        __syncthreads();
#pragma unroll
        for (int kk = 0; kk < 2; ++kk) {
            s16x8 af[4], bfr[4];
            int cgx = ((kk * 4 + q) ^ l7) << 3;
#pragma unroll
            for (int mi = 0; mi < 4; ++mi)
                af[mi] = *(const s16x8*)&Bs[(wm * 64 + mi * 16 + l15) * 64 + cgx];
#pragma unroll
            for (int ni = 0; ni < 4; ++ni)
                bfr[ni] = *(const s16x8*)&As[(wn * 64 + ni * 16 + l15) * 64 + cgx];
#pragma unroll
            for (int mi = 0; mi < 4; ++mi)
#pragma unroll
                for (int ni = 0; ni < 4; ++ni)
                    acc[mi][ni] = __builtin_amdgcn_mfma_f32_16x16x32_bf16(
                        af[mi], bfr[ni], acc[mi][ni], 0, 0, 0);
        }
        __syncthreads();
    }

    float* dst = uTp + kq * 3276800;
#pragma unroll
    for (int mi = 0; mi < 4; ++mi) {
        int co = n0 + wm * 64 + mi * 16 + q * 4;
#pragma unroll
        for (int ni = 0; ni < 4; ++ni) {
            int p = m0 + wn * 64 + ni * 16 + l15;
#pragma unroll
            for (int r = 0; r < 4; ++r)
                dst[(co + r) * 12800 + p] = acc[mi][ni][r];
        }
    }
}

// ---------------- squash + u_hat (sums K-split partials, adds prim bias) ----------------
__global__ __launch_bounds__(256) void k_squash_uhat(
    const float* __restrict__ uTp, int nkq, const float* __restrict__ pb,
    const float* __restrict__ dW, float* __restrict__ uh)
{
    int t = threadIdx.x & 31;
    int g = threadIdx.x >> 5;
    int cap = blockIdx.x * 8 + g;      // b*12800 + r
    int b = cap / 12800;
    int r = cap - b * 12800;
    int c = r / 50;
    int s = r - c * 50;
    const float* up = uTp + c * 12800 + b * 1600 + s * 32 + t;
    float u = pb[c];
#pragma unroll 4
    for (int qq = 0; qq < nkq; ++qq) u += up[qq * 3276800];
    float sn = u * u;
#pragma unroll
    for (int off = 16; off; off >>= 1) sn += __shfl_xor(sn, off, 32);
    float scale = sqrtf(sn) / (1.0f + sn);
    float us = u * scale;
    const float* wp = dW + r * 320 + t;
#pragma unroll 1
    for (int cc = 0; cc < 10; ++cc) {
        float p = wp[cc * 32] * us;
#pragma unroll
        for (int off = 16; off; off >>= 1) p += __shfl_xor(p, off, 32);
        if (t == 0) uh[(cc * 8 + b) * 12800 + r] = p;
    }
}

// ---------------- routing ----------------
// accum layout: [10 Z][80 S(c*8+b)]
__global__ __launch_bounds__(256) void k_route1(
    const float* __restrict__ uh, const float* __restrict__ bcr,
    float* __restrict__ accum, int first)
{
    int c = blockIdx.x / 10;
    int rc = blockIdx.x - c * 10;
    int r0 = rc * 1280 + threadIdx.x;
    float esum = 0.f, p[8];
#pragma unroll
    for (int b = 0; b < 8; ++b) p[b] = 0.f;
#pragma unroll 1
    for (int rr = 0; rr < 5; ++rr) {
        int r = r0 + rr * 256;
        float e = first ? 1.0f : expf(bcr[c * 12800 + r]);
        esum += e;
#pragma unroll
        for (int b = 0; b < 8; ++b)
            p[b] += e * uh[(c * 8 + b) * 12800 + r];
    }
    esum = wave_sum64(esum);
#pragma unroll
    for (int b = 0; b < 8; ++b) p[b] = wave_sum64(p[b]);
    if ((threadIdx.x & 63) == 0) {
        atomicAdd(&accum[c], esum);
#pragma unroll
        for (int b = 0; b < 8; ++b) atomicAdd(&accum[10 + c * 8 + b], p[b]);
    }
}

__global__ void k_route2(const float* __restrict__ accum, float* __restrict__ vbuf,
                         float* __restrict__ out, int first, int writeOut)
{
    int i = threadIdx.x;
    if (i >= 80) return;
    int b = i / 10, c = i - b * 10;
    float Z = first ? 12800.0f : accum[c];
    float S = accum[10 + c * 8 + b];
    float s = S / Z;
    float v = s * fabsf(s) / (1.0f + s * s);
    vbuf[i] = v;                 // [b*10+c]
    if (writeOut) out[i] = v;    // v output (8,10,1)
}

__global__ __launch_bounds__(256) void k_route3(
    const float* __restrict__ uh, const float* __restrict__ vbuf,
    float* __restrict__ bcr, int first)
{
    int c = blockIdx.x / 10;
    int rc = blockIdx.x - c * 10;
    float vb[8];
#pragma unroll
    for (int b = 0; b < 8; ++b) vb[b] = vbuf[b * 10 + c];
#pragma unroll 1
    for (int rr = 0; rr < 5; ++rr) {
        int r = rc * 1280 + threadIdx.x + rr * 256;
        float a = 0.f;
#pragma unroll
        for (int b = 0; b < 8; ++b)
            a += uh[(c * 8 + b) * 12800 + r] * vb[b];
        bcr[c * 12800 + r] = first ? a : (bcr[c * 12800 + r] + a);
    }
}

// ---------------- decoder ----------------
__global__ void k_dec1(const float* __restrict__ vbuf, const float* __restrict__ w1,
                       const float* __restrict__ b1, float* __restrict__ r1)
{
    __shared__ float ts[80];
    int j = threadIdx.x;  // 512
    if (j < 80) ts[j] = vbuf[j];
    __syncthreads();
    float acc[8];
    float bb = b1[j];
#pragma unroll
    for (int b = 0; b < 8; ++b) acc[b] = bb;
#pragma unroll 1
    for (int k = 0; k < 10; ++k) {
        float wv = w1[k * 512 + j];
#pragma unroll
        for (int b = 0; b < 8; ++b) acc[b] = fmaf(ts[b * 10 + k], wv, acc[b]);
    }
#pragma unroll
    for (int b = 0; b < 8; ++b) r1[b * 512 + j] = fmaxf(acc[b], 0.f);
}

// dec2 split over k: grid (jb 0..3, kc 0..7), partials atomically into r2p
__global__ __launch_bounds__(256) void k_dec2p(
    const float* __restrict__ r1, const float* __restrict__ w2,
    float* __restrict__ r2p)
{
    __shared__ float s1[512];
    int jb = blockIdx.x & 3, kc = blockIdx.x >> 2;
    int k0 = kc * 64;
    int tid = threadIdx.x;
    for (int i = tid; i < 512; i += 256)
        s1[i] = r1[(i >> 6) * 512 + k0 + (i & 63)];
    __syncthreads();
    int j = jb * 256 + tid;
    float acc[8];
#pragma unroll
    for (int b = 0; b < 8; ++b) acc[b] = 0.f;
    const float* wp = w2 + k0 * 1024 + j;
#pragma unroll 2
    for (int kk = 0; kk < 64; ++kk) {
        float wv = wp[kk * 1024];
#pragma unroll
        for (int b = 0; b < 8; ++b) acc[b] = fmaf(s1[b * 64 + kk], wv, acc[b]);
    }
#pragma unroll
    for (int b = 0; b < 8; ++b) atomicAdd(&r2p[b * 1024 + j], acc[b]);
}

__global__ void k_dec2f(const float* __restrict__ r2p, const float* __restrict__ b2,
                        float* __restrict__ r2)
{
    int i = blockIdx.x * 256 + threadIdx.x;  // 8192
    float v = r2p[i] + b2[i & 1023];
    r2[i] = v > 0.f ? v : 0.f;
}

// dec3 split over k: grid 1728 = (jb 0..215) x (kc 0..7)
__global__ __launch_bounds__(128) void k_dec3p(
    const float* __restrict__ r2, const float* __restrict__ w3,
    float* __restrict__ out3p)
{
    __shared__ float s2[1024];
    int jb = blockIdx.x % 216;
    int kc = blockIdx.x / 216;
    int tid = threadIdx.x;
    for (int i = tid; i < 1024; i += 128)
        s2[i] = r2[(i >> 7) * 1024 + kc * 128 + (i & 127)];
    __syncthreads();
    int j = jb * 128 + tid;
    float acc[8];
#pragma unroll
    for (int b = 0; b < 8; ++b) acc[b] = 0.f;
    const float* wp = w3 + kc * 128 * 27648 + j;
#pragma unroll 4
    for (int kk = 0; kk < 128; ++kk) {
        float wv = wp[kk * 27648];
#pragma unroll
        for (int b = 0; b < 8; ++b) acc[b] = fmaf(s2[b * 128 + kk], wv, acc[b]);
    }
#pragma unroll
    for (int b = 0; b < 8; ++b) atomicAdd(&out3p[b * 27648 + j], acc[b]);
}

__global__ void k_dec3f(const float* __restrict__ out3p, const float* __restrict__ b3,
                        float* __restrict__ out)
{
    int j = blockIdx.x * 256 + threadIdx.x;   // 27648
    int b = blockIdx.y;
    float v = out3p[b * 27648 + j] + b3[j];
    out[80 + b * 27648 + j] = 1.0f / (1.0f + expf(-v));
}

// ---------------- launch ----------------
extern "C" void kernel_launch(void* const* d_in, const int* in_sizes, int n_in,
                              void* d_out, int out_size, void* d_ws, size_t ws_size,
                              hipStream_t stream)
{
    const float* x     = (const float*)d_in[0];
    const float* c1w   = (const float*)d_in[1];
    const float* c1b   = (const float*)d_in[2];
    const float* pw    = (const float*)d_in[3];
    const float* pbias = (const float*)d_in[4];
    const float* dW    = (const float*)d_in[5];
    const float* dw1   = (const float*)d_in[6];
    const float* db1   = (const float*)d_in[7];
    const float* dw2   = (const float*)d_in[8];
    const float* db2   = (const float*)d_in[9];
    const float* dw3   = (const float*)d_in[10];
    const float* db3   = (const float*)d_in[11];
    float* out = (float*)d_out;

    char* ws = (char*)d_ws;
    u16*   h     = (u16*)(ws);                    // 31,719,424
    u16*   wt2   = (u16*)(ws + 31719424);         // 10,616,832
    float* w1t   = (float*)(ws + 42336256);       //    248,832
    float* uh    = (float*)(ws + 42585088);       //  4,096,000
    float* bcr   = (float*)(ws + 46681088);       //    512,000
    float* zbase = (float*)(ws + 47193088);       // zeroed region:
    float* accum = zbase;                         //   288 f
    float* vbuf  = zbase + 288;                   //    80 f
    float* r2p   = zbase + 368;                   //  8192 f
    float* out3p = zbase + 8560;                  // 221184 f  (end 48,112,064)
    float* r1    = (float*)(ws + 48112064);       //     16,384
    float* r2    = (float*)(ws + 48128448);       //     32,768 -> 48,161,216
    float* uTp   = (float*)(ws + 48161280);       // nkq x 13,107,200

    // K-split factor bounded by available workspace
    int nkq_sh = 2;
    if (ws_size < (size_t)48161280 + 4u * 13107200u) nkq_sh = 1;
    if (ws_size < (size_t)48161280 + 2u * 13107200u) nkq_sh = 0;
    int nkq = 1 << nkq_sh;

    k_zero<<<898, 256, 0, stream>>>(zbase, 229744);
    k_w1t<<<243, 256, 0, stream>>>(c1w, w1t);
    k_w2t<<<512, 256, 0, stream>>>(pw, wt2);
    k_conv1<<<704, 256, 0, stream>>>(x, w1t, c1b, h);
    k_gemm2<<<200 * nkq, 256, 0, stream>>>(h, wt2, uTp, nkq_sh);
    k_squash_uhat<<<12800, 256, 0, stream>>>(uTp, nkq, pbias, dW, uh);

    // routing iter 0 (b_ij = 0 -> uniform softmax; never reads poisoned bcr)
    k_route1<<<100, 256, 0, stream>>>(uh, bcr, accum, 1);
    k_route2<<<1, 128, 0, stream>>>(accum, vbuf, out, 1, 0);
    k_route3<<<100, 256, 0, stream>>>(uh, vbuf, bcr, 1);
    // iter 1
    k_route1<<<100, 256, 0, stream>>>(uh, bcr, accum + 96, 0);
    k_route2<<<1, 128, 0, stream>>>(accum + 96, vbuf, out, 0, 0);
    k_route3<<<100, 256, 0, stream>>>(uh, vbuf, bcr, 0);
    // iter 2 (final: writes v to out[0:80))
    k_route1<<<100, 256, 0, stream>>>(uh, bcr, accum + 192, 0);
    k_route2<<<1, 128, 0, stream>>>(accum + 192, vbuf, out, 0, 1);

    k_dec1<<<1, 512, 0, stream>>>(vbuf, dw1, db1, r1);
    k_dec2p<<<32, 256, 0, stream>>>(r1, dw2, r2p);
    k_dec2f<<<32, 256, 0, stream>>>(r2p, db2, r2);
    k_dec3p<<<1728, 128, 0, stream>>>(r2, dw3, out3p);
    dim3 g3f(108, 8);
    k_dec3f<<<g3f, 256, 0, stream>>>(out3p, db3, out);
}

// Round 3
// 594.171 us; speedup vs baseline: 2.7495x; 1.1330x over previous
//
#include <hip/hip_runtime.h>

typedef unsigned char u8;
typedef unsigned short u16;
typedef float f32x4 __attribute__((ext_vector_type(4)));
typedef int i32x4t __attribute__((ext_vector_type(4)));
typedef int i32x8t __attribute__((ext_vector_type(8)));

__device__ __forceinline__ u16 f2bf(float f) {
    unsigned int u = __float_as_uint(f);
    u = (u + 0x7fffu + ((u >> 16) & 1u)) >> 16;
    return (u16)u;
}

// float -> fp8 e4m3 (OCP on gfx950), saturating, low byte of packed cvt
__device__ __forceinline__ u8 f2fp8(float f) {
    int v = __builtin_amdgcn_cvt_pk_fp8_f32(f, 0.f, 0, false);
    return (u8)(v & 0xff);
}

__device__ __forceinline__ float wave_sum64(float v) {
#pragma unroll
    for (int off = 32; off; off >>= 1) v += __shfl_xor(v, off, 64);
    return v;
}

// ---------------- misc ----------------
__global__ void k_zero(float* __restrict__ p, int n) {
    int i = blockIdx.x * blockDim.x + threadIdx.x;
    if (i < n) p[i] = 0.f;
}

// conv1 weight transpose: (co,ci,ky,kx) -> [k=(ci*81+ky*9+kx)][co], fp32
__global__ void k_w1t(const float* __restrict__ w, float* __restrict__ wt) {
    int i = blockIdx.x * 256 + threadIdx.x;
    if (i >= 243 * 256) return;
    int k = i >> 8, co = i & 255;
    wt[i] = w[co * 243 + k];
}

// prim weight transpose via LDS: (co,ci,ky,kx) -> fp8 [co][(ky*9+kx)*256 + ci], x64 scale
__global__ __launch_bounds__(256) void k_w2t(const float* __restrict__ w, u8* __restrict__ wt) {
    __shared__ float ls[10368];
    int co = blockIdx.x >> 1;
    int half = blockIdx.x & 1;
    const float* src = w + (co * 256 + half * 128) * 81;
    for (int i = threadIdx.x; i < 10368; i += 256) ls[i] = src[i];
    __syncthreads();
    int ci = threadIdx.x & 127;
    int k2 = threadIdx.x >> 7;
    u8* dst = wt + co * 20736 + half * 128 + ci;
#pragma unroll 1
    for (int kk = k2; kk < 81; kk += 2)
        dst[kk * 256] = f2fp8(ls[ci * 81 + kk] * 64.0f);
}

// ---------------- conv1 + relu -> h fp8 NHWC [8][88][88][256], x16 scale ----------------
__global__ __launch_bounds__(256) void k_conv1(
    const float* __restrict__ x, const float* __restrict__ w1t,
    const float* __restrict__ b1, u8* __restrict__ h)
{
    __shared__ __align__(16) float xs[3 * 9 * 96 + 8];
    int nb = blockIdx.x;          // 0..703
    int n = nb / 88, y = nb % 88;
    int co = threadIdx.x;
    for (int i = threadIdx.x; i < 3 * 9 * 96; i += 256) {
        int ci = i / 864;
        int rem = i - ci * 864;
        int yy = rem / 96, xx = rem - yy * 96;
        xs[i] = x[((n * 3 + ci) * 96 + (y + yy)) * 96 + xx];
    }
    __syncthreads();
    float bias = b1[co];
#pragma unroll 1
    for (int xo = 0; xo < 6; ++xo) {   // 16B-aligned window tiles of 16 (last: 8 valid)
        const int xb = xo * 16;
        float acc[16];
#pragma unroll
        for (int j = 0; j < 16; ++j) acc[j] = bias;
#pragma unroll 1
        for (int cik = 0; cik < 27; ++cik) {   // ci*9+ky
            float win[24];
            const float4* row4 = (const float4*)&xs[cik * 96 + xb];
#pragma unroll
            for (int t = 0; t < 6; ++t) ((float4*)win)[t] = row4[t];
            const float* wrow = w1t + cik * 9 * 256 + co;
#pragma unroll
            for (int kx = 0; kx < 9; ++kx) {
                float wv = wrow[kx * 256];
#pragma unroll
                for (int j = 0; j < 16; ++j)
                    acc[j] = fmaf(win[kx + j], wv, acc[j]);
            }
        }
        int wlim = 88 - xb; if (wlim > 16) wlim = 16;
        u8* hp = h + ((n * 88 + y) * 88 + xb) * 256 + co;
#pragma unroll
        for (int j = 0; j < 16; ++j) {
            if (j < wlim) {
                float v = acc[j] > 0.f ? acc[j] : 0.f;
                hp[j * 256] = f2fp8(v * 16.0f);
            }
        }
    }
}

// ---------------- prim conv: implicit GEMM, MX-fp8 MFMA 16x16x128 ----------------
// uTp[kq][co][p] = sum_{K slice kq} W[co][k] * A[p][k]   (scales 2^-6 * 2^-4 in HW)
// A[p][(ky*9+kx)*256+ci] = h[n][2y+ky][2x+kx][ci] (fp8, x16), p = n*1600+y*40+x
// W fp8 x64: [co][kykx*256+ci]. K chunks of 128: G -> (kykx=G>>1, ci0=(G&1)*128).
// LDS rows 128 B; 16B-unit slot u holds global unit u^(row&7) (global-side swizzle).
__device__ __forceinline__ i32x8t frag32(const u8* __restrict__ base, int row, int q) {
    const i32x4t lo = *(const i32x4t*)(base + row * 128 + (((2 * q) ^ (row & 7)) << 4));
    const i32x4t hi = *(const i32x4t*)(base + row * 128 + (((2 * q + 1) ^ (row & 7)) << 4));
    i32x8t r;
    r[0] = lo[0]; r[1] = lo[1]; r[2] = lo[2]; r[3] = lo[3];
    r[4] = hi[0]; r[5] = hi[1]; r[6] = hi[2]; r[7] = hi[3];
    return r;
}

__global__ __launch_bounds__(512) void k_gemm2(
    const u8* __restrict__ hA, const u8* __restrict__ Wt, float* __restrict__ uTp)
{
    __shared__ __align__(16) u8 Ps[128 * 128];   // pixel rows   (MFMA B)
    __shared__ __align__(16) u8 Cs[256 * 128];   // channel rows (MFMA A)

    int blk = blockIdx.x;                 // 0..399
    int l8 = blk & 7;
    int kq = l8 >> 1;                     // XCD pair -> kq (L2-resident weight slice)
    int mt = ((blk >> 3) << 1) + (l8 & 1);   // 0..99
    int m0 = mt << 7;
    int NS = 40 + (kq < 2 ? 1 : 0);       // chunks: 41,41,40,40 (sum 162)
    int G0 = kq * 40 + (kq < 2 ? kq : 2);

    int tid = threadIdx.x;
    int wave = tid >> 6;
    int lane = tid & 63;
    int u = lane & 7;
    int lr = lane >> 3;
    int swz = (u ^ lr) << 4;

    int prow0 = wave * 8 + lr;
    int pbase[2];
#pragma unroll
    for (int ii = 0; ii < 2; ++ii) {
        int p = m0 + ii * 64 + prow0;
        int n = p / 1600;
        int rem = p - n * 1600;
        int yy = rem / 40;
        int xx = rem - yy * 40;
        pbase[ii] = ((n * 88 + 2 * yy) * 88 + 2 * xx) * 256 + swz;
    }
    int wbase[4];
#pragma unroll
    for (int ii = 0; ii < 4; ++ii)
        wbase[ii] = (ii * 64 + prow0) * 20736 + swz;

    f32x4 acc[4][4];
#pragma unroll
    for (int i = 0; i < 4; ++i)
#pragma unroll
        for (int j = 0; j < 4; ++j) acc[i][j] = (f32x4){0.f, 0.f, 0.f, 0.f};

    int wc = wave >> 1;   // channel 64-quarter
    int wp = wave & 1;    // pixel 64-half
    int q = lane >> 4;
    int l15 = lane & 15;

#pragma unroll 1
    for (int ks = 0; ks < NS; ++ks) {
        int G = G0 + ks;
        int kykx = G >> 1;
        int ci0 = (G & 1) << 7;
        int ky = kykx / 9;
        int kx = kykx - ky * 9;
        int koffA = (ky * 88 + kx) * 256 + ci0;
        int koffB = kykx * 256 + ci0;
#pragma unroll
        for (int ii = 0; ii < 2; ++ii) {
            const u8* ga = hA + pbase[ii] + koffA;
            u8* la = &Ps[(ii * 64 + wave * 8) * 128];
            __builtin_amdgcn_global_load_lds((const __attribute__((address_space(1))) void*)ga,
                                             (__attribute__((address_space(3))) void*)la, 16, 0, 0);
        }
#pragma unroll
        for (int ii = 0; ii < 4; ++ii) {
            const u8* gb = Wt + wbase[ii] + koffB;
            u8* lb = &Cs[(ii * 64 + wave * 8) * 128];
            __builtin_amdgcn_global_load_lds((const __attribute__((address_space(1))) void*)gb,
                                             (__attribute__((address_space(3))) void*)lb, 16, 0, 0);
        }
        __syncthreads();
        i32x8t af[4], bf[4];
#pragma unroll
        for (int mi = 0; mi < 4; ++mi) af[mi] = frag32(Cs, wc * 64 + mi * 16 + l15, q);
#pragma unroll
        for (int ni = 0; ni < 4; ++ni) bf[ni] = frag32(Ps, wp * 64 + ni * 16 + l15, q);
#pragma unroll
        for (int mi = 0; mi < 4; ++mi)
#pragma unroll
            for (int ni = 0; ni < 4; ++ni)
                acc[mi][ni] = __builtin_amdgcn_mfma_scale_f32_16x16x128_f8f6f4(
                    af[mi], bf[ni], acc[mi][ni], 0, 0,
                    0, 0x79797979 /*2^-6: undo W x64*/,
                    0, 0x7B7B7B7B /*2^-4: undo h x16*/);
        __syncthreads();
    }

    float* dst = uTp + kq * 3276800;
#pragma unroll
    for (int mi = 0; mi < 4; ++mi) {
        int co = wc * 64 + mi * 16 + q * 4;
#pragma unroll
        for (int ni = 0; ni < 4; ++ni) {
            int px = m0 + wp * 64 + ni * 16 + l15;
#pragma unroll
            for (int r = 0; r < 4; ++r)
                dst[(co + r) * 12800 + px] = acc[mi][ni][r];
        }
    }
}

// ---------------- squash + u_hat (sums 4 K-split partials, adds prim bias) ----------------
__global__ __launch_bounds__(256) void k_squash_uhat(
    const float* __restrict__ uTp, const float* __restrict__ pb,
    const float* __restrict__ dW, float* __restrict__ uh)
{
    int t = threadIdx.x & 31;
    int g = threadIdx.x >> 5;
    int cap = blockIdx.x * 8 + g;      // b*12800 + r
    int b = cap / 12800;
    int r = cap - b * 12800;
    int c = r / 50;
    int s = r - c * 50;
    const float* up = uTp + c * 12800 + b * 1600 + s * 32 + t;
    float u = pb[c] + up[0] + up[3276800] + up[6553600] + up[9830400];
    float sn = u * u;
#pragma unroll
    for (int off = 16; off; off >>= 1) sn += __shfl_xor(sn, off, 32);
    float scale = sqrtf(sn) / (1.0f + sn);
    float us = u * scale;
    const float* wp = dW + r * 320 + t;
#pragma unroll 1
    for (int cc = 0; cc < 10; ++cc) {
        float p = wp[cc * 32] * us;
#pragma unroll
        for (int off = 16; off; off >>= 1) p += __shfl_xor(p, off, 32);
        if (t == 0) uh[(cc * 8 + b) * 12800 + r] = p;
    }
}

// ---------------- routing ----------------
// accum layout: [10 Z][80 S(c*8+b)]
// iter-0 partial sums (uniform coupling, e == 1; Z known = 12800)
__global__ __launch_bounds__(256) void k_route1(
    const float* __restrict__ uh, float* __restrict__ accum)
{
    int c = blockIdx.x / 10;
    int rc = blockIdx.x - c * 10;
    int r0 = rc * 1280 + threadIdx.x;
    float p[8];
#pragma unroll
    for (int b = 0; b < 8; ++b) p[b] = 0.f;
#pragma unroll 1
    for (int rr = 0; rr < 5; ++rr) {
        int r = r0 + rr * 256;
#pragma unroll
        for (int b = 0; b < 8; ++b)
            p[b] += uh[(c * 8 + b) * 12800 + r];
    }
#pragma unroll
    for (int b = 0; b < 8; ++b) p[b] = wave_sum64(p[b]);
    if ((threadIdx.x & 63) == 0) {
#pragma unroll
        for (int b = 0; b < 8; ++b) atomicAdd(&accum[10 + c * 8 + b], p[b]);
    }
}

__global__ void k_route2(const float* __restrict__ accum, float* __restrict__ vbuf,
                         float* __restrict__ out, int first, int writeOut)
{
    int i = threadIdx.x;
    if (i >= 80) return;
    int b = i / 10, c = i - b * 10;
    float Z = first ? 12800.0f : accum[c];
    float S = accum[10 + c * 8 + b];
    float s = S / Z;
    float v = s * fabsf(s) / (1.0f + s * s);
    vbuf[i] = v;                 // [b*10+c]
    if (writeOut) out[i] = v;    // v output (8,10,1)
}

// fused b-update + softmax-numerator accumulation (route3 of iter i + route1 of iter i+1)
__global__ __launch_bounds__(256) void k_route31(
    const float* __restrict__ uh, const float* __restrict__ vbuf,
    float* __restrict__ bcr, float* __restrict__ accum, int first)
{
    int c = blockIdx.x / 10;
    int rc = blockIdx.x - c * 10;
    float vb[8];
#pragma unroll
    for (int b = 0; b < 8; ++b) vb[b] = vbuf[b * 10 + c];
    float esum = 0.f, p[8];
#pragma unroll
    for (int b = 0; b < 8; ++b) p[b] = 0.f;
#pragma unroll 1
    for (int rr = 0; rr < 5; ++rr) {
        int r = rc * 1280 + threadIdx.x + rr * 256;
        float uv[8];
        float a = 0.f;
#pragma unroll
        for (int b = 0; b < 8; ++b) {
            uv[b] = uh[(c * 8 + b) * 12800 + r];
            a += uv[b] * vb[b];
        }
        float bn = first ? a : (bcr[c * 12800 + r] + a);
        bcr[c * 12800 + r] = bn;
        float e = expf(bn);
        esum += e;
#pragma unroll
        for (int b = 0; b < 8; ++b) p[b] += e * uv[b];
    }
    esum = wave_sum64(esum);
#pragma unroll
    for (int b = 0; b < 8; ++b) p[b] = wave_sum64(p[b]);
    if ((threadIdx.x & 63) == 0) {
        atomicAdd(&accum[c], esum);
#pragma unroll
        for (int b = 0; b < 8; ++b) atomicAdd(&accum[10 + c * 8 + b], p[b]);
    }
}

// ---------------- decoder ----------------
__global__ void k_dec1(const float* __restrict__ vbuf, const float* __restrict__ w1,
                       const float* __restrict__ b1, float* __restrict__ r1)
{
    __shared__ float ts[80];
    int j = threadIdx.x;  // 512
    if (j < 80) ts[j] = vbuf[j];
    __syncthreads();
    float acc[8];
    float bb = b1[j];
#pragma unroll
    for (int b = 0; b < 8; ++b) acc[b] = bb;
#pragma unroll 1
    for (int k = 0; k < 10; ++k) {
        float wv = w1[k * 512 + j];
#pragma unroll
        for (int b = 0; b < 8; ++b) acc[b] = fmaf(ts[b * 10 + k], wv, acc[b]);
    }
#pragma unroll
    for (int b = 0; b < 8; ++b) r1[b * 512 + j] = fmaxf(acc[b], 0.f);
}

// dec2 split over k: grid (jb 0..3, kc 0..7); partials to r2p[kc] (no atomics)
__global__ __launch_bounds__(256) void k_dec2p(
    const float* __restrict__ r1, const float* __restrict__ w2,
    float* __restrict__ r2p)
{
    __shared__ float s1[512];
    int jb = blockIdx.x & 3, kc = blockIdx.x >> 2;
    int k0 = kc * 64;
    int tid = threadIdx.x;
    for (int i = tid; i < 512; i += 256)
        s1[i] = r1[(i >> 6) * 512 + k0 + (i & 63)];
    __syncthreads();
    int j = jb * 256 + tid;
    float acc[8];
#pragma unroll
    for (int b = 0; b < 8; ++b) acc[b] = 0.f;
    const float* wp = w2 + k0 * 1024 + j;
#pragma unroll 2
    for (int kk = 0; kk < 64; ++kk) {
        float wv = wp[kk * 1024];
#pragma unroll
        for (int b = 0; b < 8; ++b) acc[b] = fmaf(s1[b * 64 + kk], wv, acc[b]);
    }
#pragma unroll
    for (int b = 0; b < 8; ++b) r2p[kc * 8192 + b * 1024 + j] = acc[b];
}

__global__ void k_dec2f(const float* __restrict__ r2p, const float* __restrict__ b2,
                        float* __restrict__ r2)
{
    int i = blockIdx.x * 256 + threadIdx.x;  // 8192
    float v = b2[i & 1023];
#pragma unroll
    for (int kc = 0; kc < 8; ++kc) v += r2p[kc * 8192 + i];
    r2[i] = v > 0.f ? v : 0.f;
}

// dec3 split over k: grid 1728 = (jb 0..215) x (kc 0..7); partials to out3p[kc]
__global__ __launch_bounds__(128) void k_dec3p(
    const float* __restrict__ r2, const float* __restrict__ w3,
    float* __restrict__ out3p)
{
    __shared__ float s2[1024];
    int jb = blockIdx.x % 216;
    int kc = blockIdx.x / 216;
    int tid = threadIdx.x;
    for (int i = tid; i < 1024; i += 128)
        s2[i] = r2[(i >> 7) * 1024 + kc * 128 + (i & 127)];
    __syncthreads();
    int j = jb * 128 + tid;
    float acc[8];
#pragma unroll
    for (int b = 0; b < 8; ++b) acc[b] = 0.f;
    const float* wp = w3 + kc * 128 * 27648 + j;
#pragma unroll 4
    for (int kk = 0; kk < 128; ++kk) {
        float wv = wp[kk * 27648];
#pragma unroll
        for (int b = 0; b < 8; ++b) acc[b] = fmaf(s2[b * 128 + kk], wv, acc[b]);
    }
#pragma unroll
    for (int b = 0; b < 8; ++b) out3p[kc * 221184 + b * 27648 + j] = acc[b];
}

__global__ void k_dec3f(const float* __restrict__ out3p, const float* __restrict__ b3,
                        float* __restrict__ out)
{
    int j = blockIdx.x * 256 + threadIdx.x;   // 27648
    int b = blockIdx.y;
    float v = b3[j];
#pragma unroll
    for (int kc = 0; kc < 8; ++kc) v += out3p[kc * 221184 + b * 27648 + j];
    out[80 + b * 27648 + j] = 1.0f / (1.0f + expf(-v));
}

// ---------------- launch ----------------
extern "C" void kernel_launch(void* const* d_in, const int* in_sizes, int n_in,
                              void* d_out, int out_size, void* d_ws, size_t ws_size,
                              hipStream_t stream)
{
    const float* x     = (const float*)d_in[0];
    const float* c1w   = (const float*)d_in[1];
    const float* c1b   = (const float*)d_in[2];
    const float* pw    = (const float*)d_in[3];
    const float* pbias = (const float*)d_in[4];
    const float* dW    = (const float*)d_in[5];
    const float* dw1   = (const float*)d_in[6];
    const float* db1   = (const float*)d_in[7];
    const float* dw2   = (const float*)d_in[8];
    const float* db2   = (const float*)d_in[9];
    const float* dw3   = (const float*)d_in[10];
    const float* db3   = (const float*)d_in[11];
    float* out = (float*)d_out;

    char* ws = (char*)d_ws;
    u8*    h     = (u8*)(ws);                     // 15,859,712
    u8*    wt2   = (u8*)(ws + 15859712);          //  5,308,416
    float* w1t   = (float*)(ws + 21168128);       //    248,832
    float* uh    = (float*)(ws + 21416960);       //  4,096,000
    float* bcr   = (float*)(ws + 25512960);       //    512,000
    float* accum = (float*)(ws + 26024960);       //  288 f
    float* vbuf  = (float*)(ws + 26026112);       //   80 f
    float* r1    = (float*)(ws + 26026432);       //     16,384
    float* r2    = (float*)(ws + 26042816);       //     32,768
    float* r2p   = (float*)(ws + 26075584);       //    262,144 (8 slices)
    float* out3p = (float*)(ws + 26337728);       //  7,077,888 (8 slices)
    float* uTp   = (float*)(ws + 33415616);       // 52,428,800 (4 K-slices) -> 85.8 MB

    k_zero<<<2, 256, 0, stream>>>(accum, 368);    // accum(288) + vbuf(80)
    k_w1t<<<243, 256, 0, stream>>>(c1w, w1t);
    k_w2t<<<512, 256, 0, stream>>>(pw, wt2);
    k_conv1<<<704, 256, 0, stream>>>(x, w1t, c1b, h);
    k_gemm2<<<400, 512, 0, stream>>>(h, wt2, uTp);
    k_squash_uhat<<<12800, 256, 0, stream>>>(uTp, pbias, dW, uh);

    // routing iter 0 (b=0 -> uniform; Z=12800 constant)
    k_route1<<<100, 256, 0, stream>>>(uh, accum);
    k_route2<<<1, 128, 0, stream>>>(accum, vbuf, out, 1, 0);
    // fused route3(0)+route1(1)
    k_route31<<<100, 256, 0, stream>>>(uh, vbuf, bcr, accum + 96, 1);
    k_route2<<<1, 128, 0, stream>>>(accum + 96, vbuf, out, 0, 0);
    // fused route3(1)+route1(2)
    k_route31<<<100, 256, 0, stream>>>(uh, vbuf, bcr, accum + 192, 0);
    k_route2<<<1, 128, 0, stream>>>(accum + 192, vbuf, out, 0, 1);

    k_dec1<<<1, 512, 0, stream>>>(vbuf, dw1, db1, r1);
    k_dec2p<<<32, 256, 0, stream>>>(r1, dw2, r2p);
    k_dec2f<<<32, 256, 0, stream>>>(r2p, db2, r2);
    k_dec3p<<<1728, 128, 0, stream>>>(r2, dw3, out3p);
    dim3 g3f(108, 8);
    k_dec3f<<<g3f, 256, 0, stream>>>(out3p, db3, out);
}

// Round 4
// 499.516 us; speedup vs baseline: 3.2705x; 1.1895x over previous
//
#include <hip/hip_runtime.h>

typedef unsigned char u8;
typedef unsigned short u16;
typedef short s16x8 __attribute__((ext_vector_type(8)));
typedef float f32x4 __attribute__((ext_vector_type(4)));
typedef int i32x4t __attribute__((ext_vector_type(4)));
typedef int i32x8t __attribute__((ext_vector_type(8)));

__device__ __forceinline__ u16 f2bf(float f) {
    unsigned int u = __float_as_uint(f);
    u = (u + 0x7fffu + ((u >> 16) & 1u)) >> 16;
    return (u16)u;
}

// float -> fp8 e4m3 (OCP on gfx950), saturating, low byte of packed cvt
__device__ __forceinline__ u8 f2fp8(float f) {
    int v = __builtin_amdgcn_cvt_pk_fp8_f32(f, 0.f, 0, false);
    return (u8)(v & 0xff);
}

__device__ __forceinline__ float wave_sum64(float v) {
#pragma unroll
    for (int off = 32; off; off >>= 1) v += __shfl_xor(v, off, 64);
    return v;
}

// ---------------- misc ----------------
__global__ void k_zero(float* __restrict__ p, int n) {
    int i = blockIdx.x * blockDim.x + threadIdx.x;
    if (i < n) p[i] = 0.f;
}

// conv1 weight: (co,ci,ky,kx) -> bf16 [co][k], k=(ci*81+ky*9+kx), pad k 243..255 = 0
__global__ void k_w1t(const float* __restrict__ w, u16* __restrict__ wt) {
    int i = blockIdx.x * 256 + threadIdx.x;   // 65536
    int co = i >> 8, k = i & 255;
    wt[i] = (k < 243) ? f2bf(w[co * 243 + k]) : (u16)0;
}

// prim weight transpose via LDS: (co,ci,ky,kx) -> fp8 [co][(ky*9+kx)*256 + ci], x64 scale
__global__ __launch_bounds__(256) void k_w2t(const float* __restrict__ w, u8* __restrict__ wt) {
    __shared__ float ls[10368];
    int co = blockIdx.x >> 1;
    int half = blockIdx.x & 1;
    const float* src = w + (co * 256 + half * 128) * 81;
    for (int i = threadIdx.x; i < 10368; i += 256) ls[i] = src[i];
    __syncthreads();
    int ci = threadIdx.x & 127;
    int k2 = threadIdx.x >> 7;
    u8* dst = wt + co * 20736 + half * 128 + ci;
#pragma unroll 1
    for (int kk = k2; kk < 81; kk += 2)
        dst[kk * 256] = f2fp8(ls[ci * 81 + kk] * 64.0f);
}

// ---------------- conv1 im2col: x -> A[p][256] bf16, p=(n*88+y)*88+x ----------------
__global__ __launch_bounds__(256) void k_im2col(
    const float* __restrict__ x, u16* __restrict__ Abuf)
{
    __shared__ float xs[3 * 9 * 96];
    int nb = blockIdx.x;          // 0..703 = (n,y)
    int n = nb / 88, y = nb % 88;
    for (int i = threadIdx.x; i < 3 * 9 * 96; i += 256) {
        int ci = i / 864;
        int rem = i - ci * 864;
        int yy = rem / 96, xx = rem - yy * 96;
        xs[i] = x[((n * 3 + ci) * 96 + (y + yy)) * 96 + xx];
    }
    __syncthreads();
    int k = threadIdx.x;
    bool valid = k < 243;
    int lbase = 0;
    if (valid) {
        int ci = k / 81;
        int rem = k - ci * 81;
        int ky = rem / 9, kx = rem - ky * 9;
        lbase = ci * 864 + ky * 96 + kx;
    }
    u16* dst = Abuf + (size_t)nb * 88 * 256 + k;
#pragma unroll 4
    for (int x2 = 0; x2 < 88; ++x2)
        dst[x2 * 256] = valid ? f2bf(xs[lbase + x2]) : (u16)0;
}

// ---------------- conv1 GEMM: h[p][co] = relu(A[p][:] . W1[co][:] + b1[co]) -> fp8 x16 ----------------
// bf16 MFMA 16x16x32. Tile: 128 px x 256 ch, K=256 in 4 steps of 64.
// LDS rows 128 B (64 bf16); 16B unit u holds global unit u^(row&7).
__device__ __forceinline__ s16x8 fragbf(const u16* __restrict__ base, int row, int unit) {
    return *(const s16x8*)(base + row * 64 + ((unit ^ (row & 7)) << 3));
}

__global__ __launch_bounds__(512) void k_gemm1(
    const u16* __restrict__ A, const u16* __restrict__ W,
    const float* __restrict__ b1, u8* __restrict__ h)
{
    __shared__ __align__(16) u8 smem[49152];
    u16* Ps = (u16*)smem;             // 128 pixel rows   x 128 B
    u16* Cs = (u16*)(smem + 16384);   // 256 channel rows x 128 B

    int m0 = blockIdx.x << 7;         // 484 blocks
    int tid = threadIdx.x;
    int wave = tid >> 6;
    int lane = tid & 63;
    int u = lane & 7;
    int lr = lane >> 3;
    int swz = (u ^ lr) << 3;          // elems (16 B units)

    int prow = wave * 8 + lr;
    int pbase[2], wbase[4];
#pragma unroll
    for (int ii = 0; ii < 2; ++ii)
        pbase[ii] = (m0 + ii * 64 + prow) * 256 + swz;
#pragma unroll
    for (int ii = 0; ii < 4; ++ii)
        wbase[ii] = (ii * 64 + prow) * 256 + swz;

    f32x4 acc[4][4];
#pragma unroll
    for (int i = 0; i < 4; ++i)
#pragma unroll
        for (int j = 0; j < 4; ++j) acc[i][j] = (f32x4){0.f, 0.f, 0.f, 0.f};

    int wp = wave & 1;    // pixel 64-half
    int wc = wave >> 1;   // channel 64-quarter
    int q = lane >> 4;
    int l15 = lane & 15;

#pragma unroll 1
    for (int ks = 0; ks < 4; ++ks) {
        int koff = ks * 64;
#pragma unroll
        for (int ii = 0; ii < 2; ++ii) {
            const u16* ga = A + pbase[ii] + koff;
            u16* la = &Ps[(ii * 64 + wave * 8) * 64];
            __builtin_amdgcn_global_load_lds((const __attribute__((address_space(1))) void*)ga,
                                             (__attribute__((address_space(3))) void*)la, 16, 0, 0);
        }
#pragma unroll
        for (int ii = 0; ii < 4; ++ii) {
            const u16* gb = W + wbase[ii] + koff;
            u16* lb = &Cs[(ii * 64 + wave * 8) * 64];
            __builtin_amdgcn_global_load_lds((const __attribute__((address_space(1))) void*)gb,
                                             (__attribute__((address_space(3))) void*)lb, 16, 0, 0);
        }
        __syncthreads();
#pragma unroll
        for (int kk = 0; kk < 2; ++kk) {
            s16x8 af[4], bf[4];
#pragma unroll
            for (int mi = 0; mi < 4; ++mi)
                af[mi] = fragbf(Ps, wp * 64 + mi * 16 + l15, kk * 4 + q);
#pragma unroll
            for (int ni = 0; ni < 4; ++ni)
                bf[ni] = fragbf(Cs, wc * 64 + ni * 16 + l15, kk * 4 + q);
#pragma unroll
            for (int mi = 0; mi < 4; ++mi)
#pragma unroll
                for (int ni = 0; ni < 4; ++ni)
                    acc[mi][ni] = __builtin_amdgcn_mfma_f32_16x16x32_bf16(
                        af[mi], bf[ni], acc[mi][ni], 0, 0, 0);
        }
        __syncthreads();
    }

    // epilogue: bias + relu + x16 + fp8, through LDS for coalesced h stores
    float bias[4];
#pragma unroll
    for (int ni = 0; ni < 4; ++ni) bias[ni] = b1[wc * 64 + ni * 16 + l15];
#pragma unroll
    for (int mi = 0; mi < 4; ++mi)
#pragma unroll
        for (int ni = 0; ni < 4; ++ni) {
            int col = wc * 64 + ni * 16 + l15;
#pragma unroll
            for (int r = 0; r < 4; ++r) {
                int row = wp * 64 + mi * 16 + q * 4 + r;
                float v = acc[mi][ni][r] + bias[ni];
                v = v > 0.f ? v * 16.0f : 0.f;
                smem[row * 256 + col] = f2fp8(v);
            }
        }
    __syncthreads();
    const i32x4t* src = (const i32x4t*)smem;
    i32x4t* dst = (i32x4t*)(h + (size_t)m0 * 256);
#pragma unroll
    for (int i = tid; i < 2048; i += 512) dst[i] = src[i];
}

// ---------------- prim conv: implicit GEMM, MX-fp8 MFMA 16x16x128 ----------------
// uTp[kq][co][p] = sum_{K slice kq} W[co][k] * A[p][k]   (scales 2^-6 * 2^-4 in HW)
// A[p][(ky*9+kx)*256+ci] = h[n][2y+ky][2x+kx][ci] (fp8, x16), p = n*1600+y*40+x
// W fp8 x64: [co][kykx*256+ci]. K chunks of 128: G -> (kykx=G>>1, ci0=(G&1)*128).
// LDS rows 128 B; 16B-unit slot u holds global unit u^(row&7) (global-side swizzle).
__device__ __forceinline__ i32x8t frag32(const u8* __restrict__ base, int row, int q) {
    const i32x4t lo = *(const i32x4t*)(base + row * 128 + (((2 * q) ^ (row & 7)) << 4));
    const i32x4t hi = *(const i32x4t*)(base + row * 128 + (((2 * q + 1) ^ (row & 7)) << 4));
    i32x8t r;
    r[0] = lo[0]; r[1] = lo[1]; r[2] = lo[2]; r[3] = lo[3];
    r[4] = hi[0]; r[5] = hi[1]; r[6] = hi[2]; r[7] = hi[3];
    return r;
}

__global__ __launch_bounds__(512) void k_gemm2(
    const u8* __restrict__ hA, const u8* __restrict__ Wt, float* __restrict__ uTp)
{
    __shared__ __align__(16) u8 Ps[128 * 128];   // pixel rows   (MFMA A)
    __shared__ __align__(16) u8 Cs[256 * 128];   // channel rows (MFMA B)

    int blk = blockIdx.x;                 // 0..399
    int l8 = blk & 7;
    int kq = l8 >> 1;                     // XCD pair -> kq (L2-resident weight slice)
    int mt = ((blk >> 3) << 1) + (l8 & 1);   // 0..99
    int m0 = mt << 7;
    int NS = 40 + (kq < 2 ? 1 : 0);       // chunks: 41,41,40,40 (sum 162)
    int G0 = kq * 40 + (kq < 2 ? kq : 2);

    int tid = threadIdx.x;
    int wave = tid >> 6;
    int lane = tid & 63;
    int u = lane & 7;
    int lr = lane >> 3;
    int swz = (u ^ lr) << 4;

    int prow0 = wave * 8 + lr;
    int pbase[2];
#pragma unroll
    for (int ii = 0; ii < 2; ++ii) {
        int p = m0 + ii * 64 + prow0;
        int n = p / 1600;
        int rem = p - n * 1600;
        int yy = rem / 40;
        int xx = rem - yy * 40;
        pbase[ii] = ((n * 88 + 2 * yy) * 88 + 2 * xx) * 256 + swz;
    }
    int wbase[4];
#pragma unroll
    for (int ii = 0; ii < 4; ++ii)
        wbase[ii] = (ii * 64 + prow0) * 20736 + swz;

    f32x4 acc[4][4];
#pragma unroll
    for (int i = 0; i < 4; ++i)
#pragma unroll
        for (int j = 0; j < 4; ++j) acc[i][j] = (f32x4){0.f, 0.f, 0.f, 0.f};

    int wc = wave >> 1;   // channel 64-quarter
    int wp = wave & 1;    // pixel 64-half
    int q = lane >> 4;
    int l15 = lane & 15;

#pragma unroll 1
    for (int ks = 0; ks < NS; ++ks) {
        int G = G0 + ks;
        int kykx = G >> 1;
        int ci0 = (G & 1) << 7;
        int ky = kykx / 9;
        int kx = kykx - ky * 9;
        int koffA = (ky * 88 + kx) * 256 + ci0;
        int koffB = kykx * 256 + ci0;
#pragma unroll
        for (int ii = 0; ii < 2; ++ii) {
            const u8* ga = hA + pbase[ii] + koffA;
            u8* la = &Ps[(ii * 64 + wave * 8) * 128];
            __builtin_amdgcn_global_load_lds((const __attribute__((address_space(1))) void*)ga,
                                             (__attribute__((address_space(3))) void*)la, 16, 0, 0);
        }
#pragma unroll
        for (int ii = 0; ii < 4; ++ii) {
            const u8* gb = Wt + wbase[ii] + koffB;
            u8* lb = &Cs[(ii * 64 + wave * 8) * 128];
            __builtin_amdgcn_global_load_lds((const __attribute__((address_space(1))) void*)gb,
                                             (__attribute__((address_space(3))) void*)lb, 16, 0, 0);
        }
        __syncthreads();
        i32x8t af[4], bf[4];
#pragma unroll
        for (int mi = 0; mi < 4; ++mi) af[mi] = frag32(Cs, wc * 64 + mi * 16 + l15, q);
#pragma unroll
        for (int ni = 0; ni < 4; ++ni) bf[ni] = frag32(Ps, wp * 64 + ni * 16 + l15, q);
#pragma unroll
        for (int mi = 0; mi < 4; ++mi)
#pragma unroll
            for (int ni = 0; ni < 4; ++ni)
                acc[mi][ni] = __builtin_amdgcn_mfma_scale_f32_16x16x128_f8f6f4(
                    af[mi], bf[ni], acc[mi][ni], 0, 0,
                    0, 0x79797979 /*2^-6: undo W x64*/,
                    0, 0x7B7B7B7B /*2^-4: undo h x16*/);
        __syncthreads();
    }

    float* dst = uTp + kq * 3276800;
#pragma unroll
    for (int mi = 0; mi < 4; ++mi) {
        int co = wc * 64 + mi * 16 + q * 4;
#pragma unroll
        for (int ni = 0; ni < 4; ++ni) {
            int px = m0 + wp * 64 + ni * 16 + l15;
#pragma unroll
            for (int r = 0; r < 4; ++r)
                dst[(co + r) * 12800 + px] = acc[mi][ni][r];
        }
    }
}

// ---------------- squash + u_hat (warp per r, loops b; dW row read once) ----------------
__global__ __launch_bounds__(256) void k_squash_uhat(
    const float* __restrict__ uTp, const float* __restrict__ pb,
    const float* __restrict__ dW, float* __restrict__ uh)
{
    int t = threadIdx.x & 31;
    int w = threadIdx.x >> 5;
    int r = blockIdx.x * 8 + w;        // 0..12799
    int c = r / 50;
    int s = r - c * 50;
    float wreg[10];
#pragma unroll
    for (int cc = 0; cc < 10; ++cc) wreg[cc] = dW[r * 320 + cc * 32 + t];
    float pbc = pb[c];
    const float* base = uTp + c * 12800 + s * 32 + t;
#pragma unroll 1
    for (int b = 0; b < 8; ++b) {
        const float* up = base + b * 1600;
        float u = pbc + up[0] + up[3276800] + up[6553600] + up[9830400];
        float sn = u * u;
#pragma unroll
        for (int off = 16; off; off >>= 1) sn += __shfl_xor(sn, off, 32);
        float scale = sqrtf(sn) / (1.0f + sn);
        float us = u * scale;
#pragma unroll
        for (int cc = 0; cc < 10; ++cc) {
            float p = wreg[cc] * us;
#pragma unroll
            for (int off = 16; off; off >>= 1) p += __shfl_xor(p, off, 32);
            if (t == 0) uh[(cc * 8 + b) * 12800 + r] = p;
        }
    }
}

// ---------------- routing ----------------
// accum layout: [10 Z][80 S(c*8+b)]
// iter-0 partial sums (uniform coupling, e == 1; Z known = 12800)
__global__ __launch_bounds__(256) void k_route1(
    const float* __restrict__ uh, float* __restrict__ accum)
{
    int c = blockIdx.x / 10;
    int rc = blockIdx.x - c * 10;
    int r0 = rc * 1280 + threadIdx.x;
    float p[8];
#pragma unroll
    for (int b = 0; b < 8; ++b) p[b] = 0.f;
#pragma unroll 1
    for (int rr = 0; rr < 5; ++rr) {
        int r = r0 + rr * 256;
#pragma unroll
        for (int b = 0; b < 8; ++b)
            p[b] += uh[(c * 8 + b) * 12800 + r];
    }
#pragma unroll
    for (int b = 0; b < 8; ++b) p[b] = wave_sum64(p[b]);
    if ((threadIdx.x & 63) == 0) {
#pragma unroll
        for (int b = 0; b < 8; ++b) atomicAdd(&accum[10 + c * 8 + b], p[b]);
    }
}

__global__ void k_route2(const float* __restrict__ accum, float* __restrict__ vbuf,
                         float* __restrict__ out, int first, int writeOut)
{
    int i = threadIdx.x;
    if (i >= 80) return;
    int b = i / 10, c = i - b * 10;
    float Z = first ? 12800.0f : accum[c];
    float S = accum[10 + c * 8 + b];
    float s = S / Z;
    float v = s * fabsf(s) / (1.0f + s * s);
    vbuf[i] = v;                 // [b*10+c]
    if (writeOut) out[i] = v;    // v output (8,10,1)
}

// fused b-update + softmax-numerator accumulation (route3 of iter i + route1 of iter i+1)
__global__ __launch_bounds__(256) void k_route31(
    const float* __restrict__ uh, const float* __restrict__ vbuf,
    float* __restrict__ bcr, float* __restrict__ accum, int first)
{
    int c = blockIdx.x / 10;
    int rc = blockIdx.x - c * 10;
    float vb[8];
#pragma unroll
    for (int b = 0; b < 8; ++b) vb[b] = vbuf[b * 10 + c];
    float esum = 0.f, p[8];
#pragma unroll
    for (int b = 0; b < 8; ++b) p[b] = 0.f;
#pragma unroll 1
    for (int rr = 0; rr < 5; ++rr) {
        int r = rc * 1280 + threadIdx.x + rr * 256;
        float uv[8];
        float a = 0.f;
#pragma unroll
        for (int b = 0; b < 8; ++b) {
            uv[b] = uh[(c * 8 + b) * 12800 + r];
            a += uv[b] * vb[b];
        }
        float bn = first ? a : (bcr[c * 12800 + r] + a);
        bcr[c * 12800 + r] = bn;
        float e = expf(bn);
        esum += e;
#pragma unroll
        for (int b = 0; b < 8; ++b) p[b] += e * uv[b];
    }
    esum = wave_sum64(esum);
#pragma unroll
    for (int b = 0; b < 8; ++b) p[b] = wave_sum64(p[b]);
    if ((threadIdx.x & 63) == 0) {
        atomicAdd(&accum[c], esum);
#pragma unroll
        for (int b = 0; b < 8; ++b) atomicAdd(&accum[10 + c * 8 + b], p[b]);
    }
}

// ---------------- decoder ----------------
__global__ void k_dec1(const float* __restrict__ vbuf, const float* __restrict__ w1,
                       const float* __restrict__ b1, float* __restrict__ r1)
{
    __shared__ float ts[80];
    int j = threadIdx.x;  // 512
    if (j < 80) ts[j] = vbuf[j];
    __syncthreads();
    float acc[8];
    float bb = b1[j];
#pragma unroll
    for (int b = 0; b < 8; ++b) acc[b] = bb;
#pragma unroll 1
    for (int k = 0; k < 10; ++k) {
        float wv = w1[k * 512 + j];
#pragma unroll
        for (int b = 0; b < 8; ++b) acc[b] = fmaf(ts[b * 10 + k], wv, acc[b]);
    }
#pragma unroll
    for (int b = 0; b < 8; ++b) r1[b * 512 + j] = fmaxf(acc[b], 0.f);
}

// dec2 split over k: grid (jb 0..3, kc 0..7); partials to r2p[kc] (no atomics)
__global__ __launch_bounds__(256) void k_dec2p(
    const float* __restrict__ r1, const float* __restrict__ w2,
    float* __restrict__ r2p)
{
    __shared__ float s1[512];
    int jb = blockIdx.x & 3, kc = blockIdx.x >> 2;
    int k0 = kc * 64;
    int tid = threadIdx.x;
    for (int i = tid; i < 512; i += 256)
        s1[i] = r1[(i >> 6) * 512 + k0 + (i & 63)];
    __syncthreads();
    int j = jb * 256 + tid;
    float acc[8];
#pragma unroll
    for (int b = 0; b < 8; ++b) acc[b] = 0.f;
    const float* wp = w2 + k0 * 1024 + j;
#pragma unroll 2
    for (int kk = 0; kk < 64; ++kk) {
        float wv = wp[kk * 1024];
#pragma unroll
        for (int b = 0; b < 8; ++b) acc[b] = fmaf(s1[b * 64 + kk], wv, acc[b]);
    }
#pragma unroll
    for (int b = 0; b < 8; ++b) r2p[kc * 8192 + b * 1024 + j] = acc[b];
}

__global__ void k_dec2f(const float* __restrict__ r2p, const float* __restrict__ b2,
                        float* __restrict__ r2)
{
    int i = blockIdx.x * 256 + threadIdx.x;  // 8192
    float v = b2[i & 1023];
#pragma unroll
    for (int kc = 0; kc < 8; ++kc) v += r2p[kc * 8192 + i];
    r2[i] = v > 0.f ? v : 0.f;
}

// dec3 split over k: grid 1728 = (jb 0..215) x (kc 0..7); partials to out3p[kc]
__global__ __launch_bounds__(128) void k_dec3p(
    const float* __restrict__ r2, const float* __restrict__ w3,
    float* __restrict__ out3p)
{
    __shared__ float s2[1024];
    int jb = blockIdx.x % 216;
    int kc = blockIdx.x / 216;
    int tid = threadIdx.x;
    for (int i = tid; i < 1024; i += 128)
        s2[i] = r2[(i >> 7) * 1024 + kc * 128 + (i & 127)];
    __syncthreads();
    int j = jb * 128 + tid;
    float acc[8];
#pragma unroll
    for (int b = 0; b < 8; ++b) acc[b] = 0.f;
    const float* wp = w3 + kc * 128 * 27648 + j;
#pragma unroll 4
    for (int kk = 0; kk < 128; ++kk) {
        float wv = wp[kk * 27648];
#pragma unroll
        for (int b = 0; b < 8; ++b) acc[b] = fmaf(s2[b * 128 + kk], wv, acc[b]);
    }
#pragma unroll
    for (int b = 0; b < 8; ++b) out3p[kc * 221184 + b * 27648 + j] = acc[b];
}

__global__ void k_dec3f(const float* __restrict__ out3p, const float* __restrict__ b3,
                        float* __restrict__ out)
{
    int j = blockIdx.x * 256 + threadIdx.x;   // 27648
    int b = blockIdx.y;
    float v = b3[j];
#pragma unroll
    for (int kc = 0; kc < 8; ++kc) v += out3p[kc * 221184 + b * 27648 + j];
    out[80 + b * 27648 + j] = 1.0f / (1.0f + expf(-v));
}

// ---------------- launch ----------------
extern "C" void kernel_launch(void* const* d_in, const int* in_sizes, int n_in,
                              void* d_out, int out_size, void* d_ws, size_t ws_size,
                              hipStream_t stream)
{
    const float* x     = (const float*)d_in[0];
    const float* c1w   = (const float*)d_in[1];
    const float* c1b   = (const float*)d_in[2];
    const float* pw    = (const float*)d_in[3];
    const float* pbias = (const float*)d_in[4];
    const float* dW    = (const float*)d_in[5];
    const float* dw1   = (const float*)d_in[6];
    const float* db1   = (const float*)d_in[7];
    const float* dw2   = (const float*)d_in[8];
    const float* db2   = (const float*)d_in[9];
    const float* dw3   = (const float*)d_in[10];
    const float* db3   = (const float*)d_in[11];
    float* out = (float*)d_out;

    char* ws = (char*)d_ws;
    u8*    h     = (u8*)(ws);                     // 15,859,712
    u8*    wt2   = (u8*)(ws + 15859712);          //  5,308,416
    u16*   w1tb  = (u16*)(ws + 21168128);         //    131,072
    float* uh    = (float*)(ws + 21299200);       //  4,096,000
    float* bcr   = (float*)(ws + 25395200);       //    512,000
    float* accum = (float*)(ws + 25907200);       //  288 f
    float* vbuf  = (float*)(ws + 25908352);       //   80 f
    float* r1    = (float*)(ws + 25908672);       //     16,384
    float* r2    = (float*)(ws + 25925056);       //     32,768
    float* r2p   = (float*)(ws + 25957824);       //    262,144 (8 slices)
    float* out3p = (float*)(ws + 26219968);       //  7,077,888 (8 slices)
    float* uTp   = (float*)(ws + 33297856);       // 52,428,800 (4 K-slices) -> 85.7 MB
    u16*   Abuf  = (u16*)uTp;                     // 31,719,424 (dead before uTp is written)

    k_zero<<<2, 256, 0, stream>>>(accum, 368);    // accum(288) + vbuf(80)
    k_w1t<<<256, 256, 0, stream>>>(c1w, w1tb);
    k_w2t<<<512, 256, 0, stream>>>(pw, wt2);
    k_im2col<<<704, 256, 0, stream>>>(x, Abuf);
    k_gemm1<<<484, 512, 0, stream>>>(Abuf, w1tb, c1b, h);
    k_gemm2<<<400, 512, 0, stream>>>(h, wt2, uTp);
    k_squash_uhat<<<1600, 256, 0, stream>>>(uTp, pbias, dW, uh);

    // routing iter 0 (b=0 -> uniform; Z=12800 constant)
    k_route1<<<100, 256, 0, stream>>>(uh, accum);
    k_route2<<<1, 128, 0, stream>>>(accum, vbuf, out, 1, 0);
    // fused route3(0)+route1(1)
    k_route31<<<100, 256, 0, stream>>>(uh, vbuf, bcr, accum + 96, 1);
    k_route2<<<1, 128, 0, stream>>>(accum + 96, vbuf, out, 0, 0);
    // fused route3(1)+route1(2)
    k_route31<<<100, 256, 0, stream>>>(uh, vbuf, bcr, accum + 192, 0);
    k_route2<<<1, 128, 0, stream>>>(accum + 192, vbuf, out, 0, 1);

    k_dec1<<<1, 512, 0, stream>>>(vbuf, dw1, db1, r1);
    k_dec2p<<<32, 256, 0, stream>>>(r1, dw2, r2p);
    k_dec2f<<<32, 256, 0, stream>>>(r2p, db2, r2);
    k_dec3p<<<1728, 128, 0, stream>>>(r2, dw3, out3p);
    dim3 g3f(108, 8);
    k_dec3f<<<g3f, 256, 0, stream>>>(out3p, db3, out);
}

// Round 5
// 488.603 us; speedup vs baseline: 3.3435x; 1.0223x over previous
//
#include <hip/hip_runtime.h>

typedef unsigned char u8;
typedef unsigned short u16;
typedef short s16x8 __attribute__((ext_vector_type(8)));
typedef float f32x4 __attribute__((ext_vector_type(4)));
typedef int i32x4t __attribute__((ext_vector_type(4)));
typedef int i32x8t __attribute__((ext_vector_type(8)));

__device__ __forceinline__ u16 f2bf(float f) {
    unsigned int u = __float_as_uint(f);
    u = (u + 0x7fffu + ((u >> 16) & 1u)) >> 16;
    return (u16)u;
}

// float -> fp8 e4m3 (OCP on gfx950), saturating, low byte of packed cvt
__device__ __forceinline__ u8 f2fp8(float f) {
    int v = __builtin_amdgcn_cvt_pk_fp8_f32(f, 0.f, 0, false);
    return (u8)(v & 0xff);
}

__device__ __forceinline__ float wave_sum64(float v) {
#pragma unroll
    for (int off = 32; off; off >>= 1) v += __shfl_xor(v, off, 64);
    return v;
}

// ---------------- misc ----------------
__global__ void k_zero(float* __restrict__ p, int n) {
    int i = blockIdx.x * blockDim.x + threadIdx.x;
    if (i < n) p[i] = 0.f;
}

// conv1 weight: (co,ci,ky,kx) -> bf16 [co][k], k=(ci*81+ky*9+kx), pad k 243..255 = 0
__global__ void k_w1t(const float* __restrict__ w, u16* __restrict__ wt) {
    int i = blockIdx.x * 256 + threadIdx.x;   // 65536
    int co = i >> 8, k = i & 255;
    wt[i] = (k < 243) ? f2bf(w[co * 243 + k]) : (u16)0;
}

// prim weight transpose via LDS: (co,ci,ky,kx) -> fp8 [co][(ky*9+kx)*256 + ci], x64 scale
__global__ __launch_bounds__(256) void k_w2t(const float* __restrict__ w, u8* __restrict__ wt) {
    __shared__ float ls[10368];
    int co = blockIdx.x >> 1;
    int half = blockIdx.x & 1;
    const float* src = w + (co * 256 + half * 128) * 81;
    for (int i = threadIdx.x; i < 10368; i += 256) ls[i] = src[i];
    __syncthreads();
    int ci = threadIdx.x & 127;
    int k2 = threadIdx.x >> 7;
    u8* dst = wt + co * 20736 + half * 128 + ci;
#pragma unroll 1
    for (int kk = k2; kk < 81; kk += 2)
        dst[kk * 256] = f2fp8(ls[ci * 81 + kk] * 64.0f);
}

// ---------------- conv1 im2col: x -> A[p][256] bf16, p=(n*88+y)*88+x ----------------
__global__ __launch_bounds__(256) void k_im2col(
    const float* __restrict__ x, u16* __restrict__ Abuf)
{
    __shared__ float xs[3 * 9 * 96];
    int nb = blockIdx.x;          // 0..703 = (n,y)
    int n = nb / 88, y = nb % 88;
    for (int i = threadIdx.x; i < 3 * 9 * 96; i += 256) {
        int ci = i / 864;
        int rem = i - ci * 864;
        int yy = rem / 96, xx = rem - yy * 96;
        xs[i] = x[((n * 3 + ci) * 96 + (y + yy)) * 96 + xx];
    }
    __syncthreads();
    int k = threadIdx.x;
    bool valid = k < 243;
    int lbase = 0;
    if (valid) {
        int ci = k / 81;
        int rem = k - ci * 81;
        int ky = rem / 9, kx = rem - ky * 9;
        lbase = ci * 864 + ky * 96 + kx;
    }
    u16* dst = Abuf + (size_t)nb * 88 * 256 + k;
#pragma unroll 4
    for (int x2 = 0; x2 < 88; ++x2)
        dst[x2 * 256] = valid ? f2bf(xs[lbase + x2]) : (u16)0;
}

// ---------------- conv1 GEMM: h[p][co] = relu(A[p][:] . W1[co][:] + b1[co]) -> fp8 x16 ----------------
// bf16 MFMA 16x16x32. Tile: 128 px x 256 ch, K=256 in 4 steps of 64.
// LDS rows 128 B (64 bf16); 16B unit u holds global unit u^(row&7).
__device__ __forceinline__ s16x8 fragbf(const u16* __restrict__ base, int row, int unit) {
    return *(const s16x8*)(base + row * 64 + ((unit ^ (row & 7)) << 3));
}

__global__ __launch_bounds__(512) void k_gemm1(
    const u16* __restrict__ A, const u16* __restrict__ W,
    const float* __restrict__ b1, u8* __restrict__ h)
{
    __shared__ __align__(16) u8 smem[49152];
    u16* Ps = (u16*)smem;             // 128 pixel rows   x 128 B
    u16* Cs = (u16*)(smem + 16384);   // 256 channel rows x 128 B

    int m0 = blockIdx.x << 7;         // 484 blocks
    int tid = threadIdx.x;
    int wave = tid >> 6;
    int lane = tid & 63;
    int u = lane & 7;
    int lr = lane >> 3;
    int swz = (u ^ lr) << 3;          // elems (16 B units)

    int prow = wave * 8 + lr;
    int pbase[2], wbase[4];
#pragma unroll
    for (int ii = 0; ii < 2; ++ii)
        pbase[ii] = (m0 + ii * 64 + prow) * 256 + swz;
#pragma unroll
    for (int ii = 0; ii < 4; ++ii)
        wbase[ii] = (ii * 64 + prow) * 256 + swz;

    f32x4 acc[4][4];
#pragma unroll
    for (int i = 0; i < 4; ++i)
#pragma unroll
        for (int j = 0; j < 4; ++j) acc[i][j] = (f32x4){0.f, 0.f, 0.f, 0.f};

    int wp = wave & 1;    // pixel 64-half
    int wc = wave >> 1;   // channel 64-quarter
    int q = lane >> 4;
    int l15 = lane & 15;

#pragma unroll 1
    for (int ks = 0; ks < 4; ++ks) {
        int koff = ks * 64;
#pragma unroll
        for (int ii = 0; ii < 2; ++ii) {
            const u16* ga = A + pbase[ii] + koff;
            u16* la = &Ps[(ii * 64 + wave * 8) * 64];
            __builtin_amdgcn_global_load_lds((const __attribute__((address_space(1))) void*)ga,
                                             (__attribute__((address_space(3))) void*)la, 16, 0, 0);
        }
#pragma unroll
        for (int ii = 0; ii < 4; ++ii) {
            const u16* gb = W + wbase[ii] + koff;
            u16* lb = &Cs[(ii * 64 + wave * 8) * 64];
            __builtin_amdgcn_global_load_lds((const __attribute__((address_space(1))) void*)gb,
                                             (__attribute__((address_space(3))) void*)lb, 16, 0, 0);
        }
        __syncthreads();
#pragma unroll
        for (int kk = 0; kk < 2; ++kk) {
            s16x8 af[4], bf[4];
#pragma unroll
            for (int mi = 0; mi < 4; ++mi)
                af[mi] = fragbf(Ps, wp * 64 + mi * 16 + l15, kk * 4 + q);
#pragma unroll
            for (int ni = 0; ni < 4; ++ni)
                bf[ni] = fragbf(Cs, wc * 64 + ni * 16 + l15, kk * 4 + q);
#pragma unroll
            for (int mi = 0; mi < 4; ++mi)
#pragma unroll
                for (int ni = 0; ni < 4; ++ni)
                    acc[mi][ni] = __builtin_amdgcn_mfma_f32_16x16x32_bf16(
                        af[mi], bf[ni], acc[mi][ni], 0, 0, 0);
        }
        __syncthreads();
    }

    // epilogue: bias + relu + x16 + fp8, through LDS for coalesced h stores
    float bias[4];
#pragma unroll
    for (int ni = 0; ni < 4; ++ni) bias[ni] = b1[wc * 64 + ni * 16 + l15];
#pragma unroll
    for (int mi = 0; mi < 4; ++mi)
#pragma unroll
        for (int ni = 0; ni < 4; ++ni) {
            int col = wc * 64 + ni * 16 + l15;
#pragma unroll
            for (int r = 0; r < 4; ++r) {
                int row = wp * 64 + mi * 16 + q * 4 + r;
                float v = acc[mi][ni][r] + bias[ni];
                v = v > 0.f ? v * 16.0f : 0.f;
                smem[row * 256 + col] = f2fp8(v);
            }
        }
    __syncthreads();
    const i32x4t* src = (const i32x4t*)smem;
    i32x4t* dst = (i32x4t*)(h + (size_t)m0 * 256);
#pragma unroll
    for (int i = tid; i < 2048; i += 512) dst[i] = src[i];
}

// ---------------- prim conv: implicit GEMM, MX-fp8 MFMA 16x16x128 ----------------
// Tile: 128 px x 128 ch (channel-split x2) -> grid 800 = 100 mt x (kq,chb);
// 256 threads, 32 KB LDS, 4-5 blocks/CU co-resident for latency hiding.
// uTp[kq][co][p] = sum_{K slice kq} W[co][k] * A[p][k]   (scales 2^-6 * 2^-4 in HW)
// A[p][(ky*9+kx)*256+ci] = h[n][2y+ky][2x+kx][ci] (fp8, x16), p = n*1600+y*40+x
// W fp8 x64: [co][kykx*256+ci]. K chunks of 128: G -> (kykx=G>>1, ci0=(G&1)*128).
// LDS rows 128 B; 16B-unit slot u holds global unit u^(row&7) (global-side swizzle).
__device__ __forceinline__ i32x8t frag32(const u8* __restrict__ base, int row, int q) {
    const i32x4t lo = *(const i32x4t*)(base + row * 128 + (((2 * q) ^ (row & 7)) << 4));
    const i32x4t hi = *(const i32x4t*)(base + row * 128 + (((2 * q + 1) ^ (row & 7)) << 4));
    i32x8t r;
    r[0] = lo[0]; r[1] = lo[1]; r[2] = lo[2]; r[3] = lo[3];
    r[4] = hi[0]; r[5] = hi[1]; r[6] = hi[2]; r[7] = hi[3];
    return r;
}

__global__ __launch_bounds__(256) void k_gemm2(
    const u8* __restrict__ hA, const u8* __restrict__ Wt, float* __restrict__ uTp)
{
    __shared__ __align__(16) u8 Ps[128 * 128];   // pixel rows
    __shared__ __align__(16) u8 Cs[128 * 128];   // channel rows

    int blk = blockIdx.x;                 // 0..799
    int l8 = blk & 7;                     // XCD -> fixed (kq, chb): B slice L2-resident
    int kq = l8 >> 1;
    int chb = l8 & 1;
    int mt = blk >> 3;                    // 0..99
    int m0 = mt << 7;
    int c0 = chb << 7;
    int NS = 40 + (kq < 2 ? 1 : 0);       // K chunks: 41,41,40,40 (sum 162)
    int G0 = kq * 40 + (kq < 2 ? kq : 2);

    int tid = threadIdx.x;
    int wave = tid >> 6;
    int lane = tid & 63;
    int u = lane & 7;
    int lr = lane >> 3;
    int swz = (u ^ lr) << 4;

    int pbase[4], wbase[4];
#pragma unroll
    for (int ii = 0; ii < 4; ++ii) {
        int row = ii * 32 + wave * 8 + lr;
        int p = m0 + row;
        int n = p / 1600;
        int rem = p - n * 1600;
        int yy = rem / 40;
        int xx = rem - yy * 40;
        pbase[ii] = ((n * 88 + 2 * yy) * 88 + 2 * xx) * 256 + swz;
        wbase[ii] = (c0 + row) * 20736 + swz;
    }

    f32x4 acc[4][4];
#pragma unroll
    for (int i = 0; i < 4; ++i)
#pragma unroll
        for (int j = 0; j < 4; ++j) acc[i][j] = (f32x4){0.f, 0.f, 0.f, 0.f};

    int wp = wave & 1;    // pixel 64-half
    int wc = wave >> 1;   // channel 64-half
    int q = lane >> 4;
    int l15 = lane & 15;

#pragma unroll 1
    for (int ks = 0; ks < NS; ++ks) {
        int G = G0 + ks;
        int kykx = G >> 1;
        int ci0 = (G & 1) << 7;
        int ky = kykx / 9;
        int kx = kykx - ky * 9;
        int koffA = (ky * 88 + kx) * 256 + ci0;
        int koffB = kykx * 256 + ci0;
#pragma unroll
        for (int ii = 0; ii < 4; ++ii) {
            const u8* ga = hA + pbase[ii] + koffA;
            u8* la = &Ps[(ii * 32 + wave * 8) * 128];
            __builtin_amdgcn_global_load_lds((const __attribute__((address_space(1))) void*)ga,
                                             (__attribute__((address_space(3))) void*)la, 16, 0, 0);
            const u8* gb = Wt + wbase[ii] + koffB;
            u8* lb = &Cs[(ii * 32 + wave * 8) * 128];
            __builtin_amdgcn_global_load_lds((const __attribute__((address_space(1))) void*)gb,
                                             (__attribute__((address_space(3))) void*)lb, 16, 0, 0);
        }
        __syncthreads();
        i32x8t af[4], bf[4];
#pragma unroll
        for (int mi = 0; mi < 4; ++mi) af[mi] = frag32(Cs, wc * 64 + mi * 16 + l15, q);
#pragma unroll
        for (int ni = 0; ni < 4; ++ni) bf[ni] = frag32(Ps, wp * 64 + ni * 16 + l15, q);
#pragma unroll
        for (int mi = 0; mi < 4; ++mi)
#pragma unroll
            for (int ni = 0; ni < 4; ++ni)
                acc[mi][ni] = __builtin_amdgcn_mfma_scale_f32_16x16x128_f8f6f4(
                    af[mi], bf[ni], acc[mi][ni], 0, 0,
                    0, 0x79797979 /*2^-6: undo W x64*/,
                    0, 0x7B7B7B7B /*2^-4: undo h x16*/);
        __syncthreads();
    }

    float* dst = uTp + kq * 3276800;
#pragma unroll
    for (int mi = 0; mi < 4; ++mi) {
        int co = c0 + wc * 64 + mi * 16 + q * 4;
#pragma unroll
        for (int ni = 0; ni < 4; ++ni) {
            int px = m0 + wp * 64 + ni * 16 + l15;
#pragma unroll
            for (int r = 0; r < 4; ++r)
                dst[(co + r) * 12800 + px] = acc[mi][ni][r];
        }
    }
}

// ---------------- squash + u_hat (warp per r, loops b; dW row read once) ----------------
__global__ __launch_bounds__(256) void k_squash_uhat(
    const float* __restrict__ uTp, const float* __restrict__ pb,
    const float* __restrict__ dW, float* __restrict__ uh)
{
    int t = threadIdx.x & 31;
    int w = threadIdx.x >> 5;
    int r = blockIdx.x * 8 + w;        // 0..12799
    int c = r / 50;
    int s = r - c * 50;
    float wreg[10];
#pragma unroll
    for (int cc = 0; cc < 10; ++cc) wreg[cc] = dW[r * 320 + cc * 32 + t];
    float pbc = pb[c];
    const float* base = uTp + c * 12800 + s * 32 + t;
#pragma unroll 1
    for (int b = 0; b < 8; ++b) {
        const float* up = base + b * 1600;
        float u = pbc + up[0] + up[3276800] + up[6553600] + up[9830400];
        float sn = u * u;
#pragma unroll
        for (int off = 16; off; off >>= 1) sn += __shfl_xor(sn, off, 32);
        float scale = sqrtf(sn) / (1.0f + sn);
        float us = u * scale;
#pragma unroll
        for (int cc = 0; cc < 10; ++cc) {
            float p = wreg[cc] * us;
#pragma unroll
            for (int off = 16; off; off >>= 1) p += __shfl_xor(p, off, 32);
            if (t == 0) uh[(cc * 8 + b) * 12800 + r] = p;
        }
    }
}

// ---------------- routing ----------------
// accum layout: [10 Z][80 S(c*8+b)]
// iter-0 partial sums (uniform coupling, e == 1; Z known = 12800)
__global__ __launch_bounds__(256) void k_route1(
    const float* __restrict__ uh, float* __restrict__ accum)
{
    int c = blockIdx.x / 10;
    int rc = blockIdx.x - c * 10;
    int r0 = rc * 1280 + threadIdx.x;
    float p[8];
#pragma unroll
    for (int b = 0; b < 8; ++b) p[b] = 0.f;
#pragma unroll 1
    for (int rr = 0; rr < 5; ++rr) {
        int r = r0 + rr * 256;
#pragma unroll
        for (int b = 0; b < 8; ++b)
            p[b] += uh[(c * 8 + b) * 12800 + r];
    }
#pragma unroll
    for (int b = 0; b < 8; ++b) p[b] = wave_sum64(p[b]);
    if ((threadIdx.x & 63) == 0) {
#pragma unroll
        for (int b = 0; b < 8; ++b) atomicAdd(&accum[10 + c * 8 + b], p[b]);
    }
}

__global__ void k_route2(const float* __restrict__ accum, float* __restrict__ vbuf,
                         float* __restrict__ out, int first, int writeOut)
{
    int i = threadIdx.x;
    if (i >= 80) return;
    int b = i / 10, c = i - b * 10;
    float Z = first ? 12800.0f : accum[c];
    float S = accum[10 + c * 8 + b];
    float s = S / Z;
    float v = s * fabsf(s) / (1.0f + s * s);
    vbuf[i] = v;                 // [b*10+c]
    if (writeOut) out[i] = v;    // v output (8,10,1)
}

// fused b-update + softmax-numerator accumulation (route3 of iter i + route1 of iter i+1)
__global__ __launch_bounds__(256) void k_route31(
    const float* __restrict__ uh, const float* __restrict__ vbuf,
    float* __restrict__ bcr, float* __restrict__ accum, int first)
{
    int c = blockIdx.x / 10;
    int rc = blockIdx.x - c * 10;
    float vb[8];
#pragma unroll
    for (int b = 0; b < 8; ++b) vb[b] = vbuf[b * 10 + c];
    float esum = 0.f, p[8];
#pragma unroll
    for (int b = 0; b < 8; ++b) p[b] = 0.f;
#pragma unroll 1
    for (int rr = 0; rr < 5; ++rr) {
        int r = rc * 1280 + threadIdx.x + rr * 256;
        float uv[8];
        float a = 0.f;
#pragma unroll
        for (int b = 0; b < 8; ++b) {
            uv[b] = uh[(c * 8 + b) * 12800 + r];
            a += uv[b] * vb[b];
        }
        float bn = first ? a : (bcr[c * 12800 + r] + a);
        bcr[c * 12800 + r] = bn;
        float e = expf(bn);
        esum += e;
#pragma unroll
        for (int b = 0; b < 8; ++b) p[b] += e * uv[b];
    }
    esum = wave_sum64(esum);
#pragma unroll
    for (int b = 0; b < 8; ++b) p[b] = wave_sum64(p[b]);
    if ((threadIdx.x & 63) == 0) {
        atomicAdd(&accum[c], esum);
#pragma unroll
        for (int b = 0; b < 8; ++b) atomicAdd(&accum[10 + c * 8 + b], p[b]);
    }
}

// ---------------- decoder ----------------
__global__ void k_dec1(const float* __restrict__ vbuf, const float* __restrict__ w1,
                       const float* __restrict__ b1, float* __restrict__ r1)
{
    __shared__ float ts[80];
    int j = threadIdx.x;  // 512
    if (j < 80) ts[j] = vbuf[j];
    __syncthreads();
    float acc[8];
    float bb = b1[j];
#pragma unroll
    for (int b = 0; b < 8; ++b) acc[b] = bb;
#pragma unroll 1
    for (int k = 0; k < 10; ++k) {
        float wv = w1[k * 512 + j];
#pragma unroll
        for (int b = 0; b < 8; ++b) acc[b] = fmaf(ts[b * 10 + k], wv, acc[b]);
    }
#pragma unroll
    for (int b = 0; b < 8; ++b) r1[b * 512 + j] = fmaxf(acc[b], 0.f);
}

// dec2 split over k: grid (jb 0..3, kc 0..7); partials to r2p[kc] (no atomics)
__global__ __launch_bounds__(256) void k_dec2p(
    const float* __restrict__ r1, const float* __restrict__ w2,
    float* __restrict__ r2p)
{
    __shared__ float s1[512];
    int jb = blockIdx.x & 3, kc = blockIdx.x >> 2;
    int k0 = kc * 64;
    int tid = threadIdx.x;
    for (int i = tid; i < 512; i += 256)
        s1[i] = r1[(i >> 6) * 512 + k0 + (i & 63)];
    __syncthreads();
    int j = jb * 256 + tid;
    float acc[8];
#pragma unroll
    for (int b = 0; b < 8; ++b) acc[b] = 0.f;
    const float* wp = w2 + k0 * 1024 + j;
#pragma unroll 2
    for (int kk = 0; kk < 64; ++kk) {
        float wv = wp[kk * 1024];
#pragma unroll
        for (int b = 0; b < 8; ++b) acc[b] = fmaf(s1[b * 64 + kk], wv, acc[b]);
    }
#pragma unroll
    for (int b = 0; b < 8; ++b) r2p[kc * 8192 + b * 1024 + j] = acc[b];
}

__global__ void k_dec2f(const float* __restrict__ r2p, const float* __restrict__ b2,
                        float* __restrict__ r2)
{
    int i = blockIdx.x * 256 + threadIdx.x;  // 8192
    float v = b2[i & 1023];
#pragma unroll
    for (int kc = 0; kc < 8; ++kc) v += r2p[kc * 8192 + i];
    r2[i] = v > 0.f ? v : 0.f;
}

// dec3 split over k: grid 1728 = (jb 0..215) x (kc 0..7); partials to out3p[kc]
__global__ __launch_bounds__(128) void k_dec3p(
    const float* __restrict__ r2, const float* __restrict__ w3,
    float* __restrict__ out3p)
{
    __shared__ float s2[1024];
    int jb = blockIdx.x % 216;
    int kc = blockIdx.x / 216;
    int tid = threadIdx.x;
    for (int i = tid; i < 1024; i += 128)
        s2[i] = r2[(i >> 7) * 1024 + kc * 128 + (i & 127)];
    __syncthreads();
    int j = jb * 128 + tid;
    float acc[8];
#pragma unroll
    for (int b = 0; b < 8; ++b) acc[b] = 0.f;
    const float* wp = w3 + kc * 128 * 27648 + j;
#pragma unroll 4
    for (int kk = 0; kk < 128; ++kk) {
        float wv = wp[kk * 27648];
#pragma unroll
        for (int b = 0; b < 8; ++b) acc[b] = fmaf(s2[b * 128 + kk], wv, acc[b]);
    }
#pragma unroll
    for (int b = 0; b < 8; ++b) out3p[kc * 221184 + b * 27648 + j] = acc[b];
}

__global__ void k_dec3f(const float* __restrict__ out3p, const float* __restrict__ b3,
                        float* __restrict__ out)
{
    int j = blockIdx.x * 256 + threadIdx.x;   // 27648
    int b = blockIdx.y;
    float v = b3[j];
#pragma unroll
    for (int kc = 0; kc < 8; ++kc) v += out3p[kc * 221184 + b * 27648 + j];
    out[80 + b * 27648 + j] = 1.0f / (1.0f + expf(-v));
}

// ---------------- launch ----------------
extern "C" void kernel_launch(void* const* d_in, const int* in_sizes, int n_in,
                              void* d_out, int out_size, void* d_ws, size_t ws_size,
                              hipStream_t stream)
{
    const float* x     = (const float*)d_in[0];
    const float* c1w   = (const float*)d_in[1];
    const float* c1b   = (const float*)d_in[2];
    const float* pw    = (const float*)d_in[3];
    const float* pbias = (const float*)d_in[4];
    const float* dW    = (const float*)d_in[5];
    const float* dw1   = (const float*)d_in[6];
    const float* db1   = (const float*)d_in[7];
    const float* dw2   = (const float*)d_in[8];
    const float* db2   = (const float*)d_in[9];
    const float* dw3   = (const float*)d_in[10];
    const float* db3   = (const float*)d_in[11];
    float* out = (float*)d_out;

    char* ws = (char*)d_ws;
    u8*    h     = (u8*)(ws);                     // 15,859,712
    u8*    wt2   = (u8*)(ws + 15859712);          //  5,308,416
    u16*   w1tb  = (u16*)(ws + 21168128);         //    131,072
    float* uh    = (float*)(ws + 21299200);       //  4,096,000
    float* bcr   = (float*)(ws + 25395200);       //    512,000
    float* accum = (float*)(ws + 25907200);       //  288 f
    float* vbuf  = (float*)(ws + 25908352);       //   80 f
    float* r1    = (float*)(ws + 25908672);       //     16,384
    float* r2    = (float*)(ws + 25925056);       //     32,768
    float* r2p   = (float*)(ws + 25957824);       //    262,144 (8 slices)
    float* out3p = (float*)(ws + 26219968);       //  7,077,888 (8 slices)
    float* uTp   = (float*)(ws + 33297856);       // 52,428,800 (4 K-slices) -> 85.7 MB
    u16*   Abuf  = (u16*)uTp;                     // 31,719,424 (dead before uTp is written)

    k_zero<<<2, 256, 0, stream>>>(accum, 368);    // accum(288) + vbuf(80)
    k_w1t<<<256, 256, 0, stream>>>(c1w, w1tb);
    k_w2t<<<512, 256, 0, stream>>>(pw, wt2);
    k_im2col<<<704, 256, 0, stream>>>(x, Abuf);
    k_gemm1<<<484, 512, 0, stream>>>(Abuf, w1tb, c1b, h);
    k_gemm2<<<800, 256, 0, stream>>>(h, wt2, uTp);
    k_squash_uhat<<<1600, 256, 0, stream>>>(uTp, pbias, dW, uh);

    // routing iter 0 (b=0 -> uniform; Z=12800 constant)
    k_route1<<<100, 256, 0, stream>>>(uh, accum);
    k_route2<<<1, 128, 0, stream>>>(accum, vbuf, out, 1, 0);
    // fused route3(0)+route1(1)
    k_route31<<<100, 256, 0, stream>>>(uh, vbuf, bcr, accum + 96, 1);
    k_route2<<<1, 128, 0, stream>>>(accum + 96, vbuf, out, 0, 0);
    // fused route3(1)+route1(2)
    k_route31<<<100, 256, 0, stream>>>(uh, vbuf, bcr, accum + 192, 0);
    k_route2<<<1, 128, 0, stream>>>(accum + 192, vbuf, out, 0, 1);

    k_dec1<<<1, 512, 0, stream>>>(vbuf, dw1, db1, r1);
    k_dec2p<<<32, 256, 0, stream>>>(r1, dw2, r2p);
    k_dec2f<<<32, 256, 0, stream>>>(r2p, db2, r2);
    k_dec3p<<<1728, 128, 0, stream>>>(r2, dw3, out3p);
    dim3 g3f(108, 8);
    k_dec3f<<<g3f, 256, 0, stream>>>(out3p, db3, out);
}